// Round 16
// baseline (393.626 us; speedup 1.0000x reference)
//
#include <hip/hip_runtime.h>
#include <math.h>

#define N_   2048
#define NPTS 32768   // B*N = 16*2048

typedef __attribute__((ext_vector_type(8))) short short8;   // 8 bf16 (4 VGPRs)
typedef __attribute__((ext_vector_type(4))) float f32x4;
typedef unsigned long long u64;

__device__ __forceinline__ unsigned short f2bf(float f) {   // RTNE
  unsigned int u = __float_as_uint(f);
  return (unsigned short)((u + 0x7fffu + ((u >> 16) & 1u)) >> 16);
}
__device__ __forceinline__ float4 max4(float4 a, float4 b) {
  return make_float4(fmaxf(a.x,b.x), fmaxf(a.y,b.y), fmaxf(a.z,b.z), fmaxf(a.w,b.w));
}

// ---------------------------------------------------------------- prep (x,y,z,|p|^2) + W_c2->bf16
__global__ __launch_bounds__(256) void k_prep2(const float* __restrict__ pts,
                                               const float* __restrict__ Wc2,
                                               float4* __restrict__ pts4,
                                               unsigned short* __restrict__ wb) {
  if (blockIdx.x < 128) {
    int P = blockIdx.x * 256 + threadIdx.x;
    float x = pts[P*3+0], y = pts[P*3+1], z = pts[P*3+2];
    float xx = __fadd_rn(__fadd_rn(__fmul_rn(x,x), __fmul_rn(y,y)), __fmul_rn(z,z));
    pts4[P] = make_float4(x, y, z, xx);
  } else {
    int i = ((blockIdx.x - 128) * 256 + threadIdx.x) * 4;
    float4 w = *(const float4*)&Wc2[i];
    *(ushort4*)&wb[i] = make_ushort4(f2bf(w.x), f2bf(w.y), f2bf(w.z), f2bf(w.w));
  }
}

// ---------------------------------------------------------------- knn (R9 — measured 106 us local optimum)
#define KCAP 32
__global__ __launch_bounds__(256) void k_knn4(const float4* __restrict__ pts4,
                                              u64* __restrict__ pk) {
  __shared__ float4 cand[512];
  __shared__ u64 ring[KCAP+1][256];   // +1 guard row for prefetch at s+1
  const int tid = threadIdx.x;
  const int qg  = blockIdx.x;      // 0..127: query group of 256
  const int ch  = blockIdx.y;      // 0..3:   candidate chunk
  const int P   = qg * 256 + tid;  // global query point
  const float4* base = pts4 + ((P >> 11) << 11);
  const int j0 = ch << 9;
  for (int i = tid; i < 512; i += 256) cand[i] = base[j0 + i];
  const float4 q = base[P & (N_-1)];
  __syncthreads();

  u64 K[16];
#pragma unroll
  for (int t = 0; t < 16; ++t) K[t] = 0ull;   // 0 < any real key -> -inf sentinel
  u64 kmin = 0ull;
  int cnt = 0;

#define FLUSH4() do { \
    int s = 0; \
    u64 fk_next = ring[0][tid]; \
    while (__any(s < cnt)) { \
      u64 fk = (s < cnt) ? fk_next : 0ull; \
      fk_next = ring[s+1][tid]; \
      if (fk > kmin) { \
        _Pragma("unroll") \
        for (int t = 15; t > 0; --t) { \
          if (K[t] < fk) K[t] = (K[t-1] < fk) ? K[t-1] : fk; \
        } \
        if (K[0] < fk) K[0] = fk; \
        kmin = K[15]; \
      } \
      ++s; \
    } \
    cnt = 0; \
  } while (0)

  for (int jj = 0; jj < 512; jj += 4) {
    if (__any(cnt > KCAP - 4)) FLUSH4();
#pragma unroll
    for (int u = 0; u < 4; ++u) {
      float4 c = cand[jj + u];
      float inner = __fadd_rn(__fadd_rn(__fmul_rn(q.x,c.x), __fmul_rn(q.y,c.y)),
                              __fmul_rn(q.z,c.z));
      float dj = __fsub_rn(__fsub_rn(__fmul_rn(2.f, inner), q.w), c.w);
      unsigned int du = __float_as_uint(dj);
      unsigned int kd = du ^ (((unsigned int)((int)du >> 31)) | 0x80000000u);
      u64 key = ((u64)kd << 32) | (unsigned int)(~(j0 + jj + u));
      if (key > kmin) { ring[cnt][tid] = key; ++cnt; }
    }
  }
  FLUSH4();
#undef FLUSH4
#pragma unroll
  for (int t = 0; t < 16; ++t)
    pk[((size_t)P*4 + ch)*16 + t] = K[t];
}

// ---------------------------------------------------------------- merge four sorted-16 lists + local_cov + m1a
// R18 PROBE: REP=5 (idempotent; Wl/bl staged once, per-rep work register-only,
// global writes rewrite identical values). mc = top5_dispatch/5. REVERT next.
#define MC_REP 5
__device__ __forceinline__ void kmerge16(const u64* a, const u64* b, u64* m) {
#pragma unroll
  for (int t = 0; t < 16; ++t) m[t] = (a[t] >= b[15-t]) ? a[t] : b[15-t];
#pragma unroll
  for (int dd = 8; dd >= 1; dd >>= 1)
#pragma unroll
    for (int i = 0; i < 16; ++i)
      if ((i & dd) == 0) {
        int j = i + dd;
        if (m[i] < m[j]) { u64 t_ = m[i]; m[i] = m[j]; m[j] = t_; }
      }
}

__global__ __launch_bounds__(256) void k_mergecov(const u64* __restrict__ pk,
                                                  const float4* __restrict__ pts4,
                                                  const float* __restrict__ W,
                                                  const float* __restrict__ bias,
                                                  int* __restrict__ idx,
                                                  float* __restrict__ act0) {
  __shared__ float Wl[64*12];
  __shared__ float bl[64];
  const int tid = threadIdx.x;
  for (int i = tid; i < 768; i += 256) Wl[i] = W[i];
  if (tid < 64) bl[tid] = bias[tid];
  __syncthreads();

  for (int rep = 0; rep < MC_REP; ++rep) {
  int P = blockIdx.x * 256 + tid;
  const u64* row = pk + (size_t)P * 64;
  u64 L0[16], L1[16], A[16], B[16], M[16];
#pragma unroll
  for (int t = 0; t < 16; ++t) { L0[t] = row[t]; L1[t] = row[16+t]; }
  kmerge16(L0, L1, A);
#pragma unroll
  for (int t = 0; t < 16; ++t) { L0[t] = row[32+t]; L1[t] = row[48+t]; }
  kmerge16(L0, L1, B);
  kmerge16(A, B, M);
#pragma unroll
  for (int t = 0; t < 16; ++t)
    idx[(size_t)P*16 + t] = (int)(~(unsigned int)(M[t] & 0xFFFFFFFFull));

  const int j0 = (int)(~(unsigned int)(M[0] & 0xFFFFFFFFull));
  const int j1 = (int)(~(unsigned int)(M[1] & 0xFFFFFFFFull));
  const float4* base = pts4 + ((P >> 11) << 11);
  float4 p  = base[P & (N_-1)];
  float4 n0 = base[j0];
  float4 n1 = base[j1];
  float f[12];
  f[0]=p.x; f[1]=p.y; f[2]=p.z;
  f[3]=n0.x*n1.x; f[4]=n0.x*n1.y; f[5]=n0.x*n1.z;
  f[6]=n0.y*n1.x; f[7]=n0.y*n1.y; f[8]=n0.y*n1.z;
  f[9]=n0.z*n1.x; f[10]=n0.z*n1.y; f[11]=n0.z*n1.z;
  float* out = act0 + (size_t)P*64;
  for (int o4 = 0; o4 < 64; o4 += 4) {
    float4 v; float* vv = (float*)&v;
#pragma unroll
    for (int u = 0; u < 4; ++u) {
      int o = o4 + u;
      float acc = bl[o];
#pragma unroll
      for (int ci = 0; ci < 12; ++ci) acc += Wl[o*12+ci] * f[ci];
      vv[u] = fmaxf(acc, 0.f);
    }
    *(float4*)&out[o4] = v;
  }
  }   // rep
}

// ---------------------------------------------------------------- fused m1b+m1c (64->64 relu, 64->64 relu)
__global__ __launch_bounds__(256) void k_m1bc(const float* __restrict__ X,
                                              const float* __restrict__ W1, const float* __restrict__ b1,
                                              const float* __restrict__ W2, const float* __restrict__ b2,
                                              float* __restrict__ Y) {
  __shared__ __align__(16) float Wt[64][68];
  __shared__ __align__(16) float Xt[64][68];
  const int tid = threadIdx.x;
  const int p0  = blockIdx.x * 64;
  const int cg = (tid & 15) * 4;
  const int pg = (tid >> 4) * 4;
  for (int i = tid; i < 4096; i += 256) {
    int r = i >> 6, k = i & 63;
    Wt[k][r] = W1[(size_t)r*64 + k];
    Xt[k][r] = X[(size_t)(p0 + r)*64 + k];
  }
  __syncthreads();
  float acc[4][4] = {{0.f,0.f,0.f,0.f},{0.f,0.f,0.f,0.f},{0.f,0.f,0.f,0.f},{0.f,0.f,0.f,0.f}};
#pragma unroll
  for (int k = 0; k < 64; ++k) {
    float4 wv = *(const float4*)&Wt[k][cg];
    float4 xv = *(const float4*)&Xt[k][pg];
    const float wr[4] = {wv.x, wv.y, wv.z, wv.w};
    const float xr[4] = {xv.x, xv.y, xv.z, xv.w};
#pragma unroll
    for (int i = 0; i < 4; ++i)
#pragma unroll
      for (int j = 0; j < 4; ++j)
        acc[i][j] += wr[i] * xr[j];
  }
  __syncthreads();
  float4 bv1 = *(const float4*)&b1[cg];
  const float br1[4] = {bv1.x, bv1.y, bv1.z, bv1.w};
#pragma unroll
  for (int i = 0; i < 4; ++i) {
    float4 v;
    v.x = fmaxf(acc[i][0] + br1[i], 0.f);
    v.y = fmaxf(acc[i][1] + br1[i], 0.f);
    v.z = fmaxf(acc[i][2] + br1[i], 0.f);
    v.w = fmaxf(acc[i][3] + br1[i], 0.f);
    *(float4*)&Xt[cg + i][pg] = v;
  }
  for (int i = tid; i < 4096; i += 256) {
    int r = i >> 6, k = i & 63;
    Wt[k][r] = W2[(size_t)r*64 + k];
  }
  __syncthreads();
  float ac2[4][4] = {{0.f,0.f,0.f,0.f},{0.f,0.f,0.f,0.f},{0.f,0.f,0.f,0.f},{0.f,0.f,0.f,0.f}};
#pragma unroll
  for (int k = 0; k < 64; ++k) {
    float4 wv = *(const float4*)&Wt[k][cg];
    float4 xv = *(const float4*)&Xt[k][pg];
    const float wr[4] = {wv.x, wv.y, wv.z, wv.w};
    const float xr[4] = {xv.x, xv.y, xv.z, xv.w};
#pragma unroll
    for (int i = 0; i < 4; ++i)
#pragma unroll
      for (int j = 0; j < 4; ++j)
        ac2[i][j] += wr[i] * xr[j];
  }
  float4 bv2 = *(const float4*)&b2[cg];
  const float br2[4] = {bv2.x, bv2.y, bv2.z, bv2.w};
#pragma unroll
  for (int j = 0; j < 4; ++j) {
    float4 st; float* sv = (float*)&st;
#pragma unroll
    for (int i = 0; i < 4; ++i) sv[i] = fmaxf(ac2[i][j] + br2[i], 0.f);
    *(float4*)&Y[(size_t)(p0 + pg + j)*64 + cg] = st;
  }
}

// ---------------------------------------------------------------- fused pool64 -> lin1 -> relu(c1): act1 -> act2 (P,128)
__global__ __launch_bounds__(256) void k_lin1c1(const float* __restrict__ A,   // act1 (P,64)
                                                const int* __restrict__ idx,
                                                const float* __restrict__ Wl1, const float* __restrict__ bl1,
                                                const float* __restrict__ Wc1, const float* __restrict__ bc1,
                                                float* __restrict__ Y) {       // act2 (P,128)
  __shared__ __align__(16) float Wt[64][68];
  __shared__ __align__(16) float Xt[64][68];
  __shared__ int il[1024];
  const int tid = threadIdx.x;
  const int p0  = blockIdx.x * 64;
  const int cg = (tid & 15) * 4;
  const int pg = (tid >> 4) * 4;
  const int gr = tid >> 2, gk = (tid & 3) * 16;
  const float* Ab = A + (size_t)((p0 >> 11) << 11) * 64;
  *(int4*)&il[tid*4] = *(const int4*)&idx[(size_t)p0*16 + tid*4];
  for (int i = tid; i < 4096; i += 256) {
    int r = i >> 6, k = i & 63;
    Wt[k][r] = Wl1[(size_t)r*64 + k];
  }
  __syncthreads();
  {
    float4 mm[4];
#pragma unroll
    for (int u = 0; u < 4; ++u) mm[u] = make_float4(-INFINITY,-INFINITY,-INFINITY,-INFINITY);
    const int* ir = &il[gr*16];
#pragma unroll
    for (int nb = 0; nb < 16; ++nb) {
      int j = ir[nb];
      const float4* row = (const float4*)&Ab[(size_t)j*64 + gk];
      mm[0] = max4(mm[0], row[0]);
      mm[1] = max4(mm[1], row[1]);
      mm[2] = max4(mm[2], row[2]);
      mm[3] = max4(mm[3], row[3]);
    }
    const float* mf = (const float*)mm;
#pragma unroll
    for (int u = 0; u < 16; ++u) Xt[gk + u][gr] = mf[u];
  }
  __syncthreads();
  float acc[4][4] = {{0.f,0.f,0.f,0.f},{0.f,0.f,0.f,0.f},{0.f,0.f,0.f,0.f},{0.f,0.f,0.f,0.f}};
#pragma unroll
  for (int k = 0; k < 64; ++k) {
    float4 wv = *(const float4*)&Wt[k][cg];
    float4 xv = *(const float4*)&Xt[k][pg];
    const float wr[4] = {wv.x, wv.y, wv.z, wv.w};
    const float xr[4] = {xv.x, xv.y, xv.z, xv.w};
#pragma unroll
    for (int i = 0; i < 4; ++i)
#pragma unroll
      for (int j = 0; j < 4; ++j)
        acc[i][j] += wr[i] * xr[j];
  }
  __syncthreads();
  float4 bv = *(const float4*)&bl1[cg];
  const float br[4] = {bv.x, bv.y, bv.z, bv.w};
#pragma unroll
  for (int i = 0; i < 4; ++i) {
    float4 v;
    v.x = acc[i][0] + br[i];
    v.y = acc[i][1] + br[i];
    v.z = acc[i][2] + br[i];
    v.w = acc[i][3] + br[i];
    *(float4*)&Xt[cg + i][pg] = v;
  }
  for (int i = tid; i < 4096; i += 256) {
    int r = i >> 6, k = i & 63;
    Wt[k][r] = Wc1[(size_t)r*64 + k];
  }
  __syncthreads();
  float ac2[4][4] = {{0.f,0.f,0.f,0.f},{0.f,0.f,0.f,0.f},{0.f,0.f,0.f,0.f},{0.f,0.f,0.f,0.f}};
#pragma unroll
  for (int k = 0; k < 64; ++k) {
    float4 wv = *(const float4*)&Wt[k][cg];
    float4 xv = *(const float4*)&Xt[k][pg];
    const float wr[4] = {wv.x, wv.y, wv.z, wv.w};
    const float xr[4] = {xv.x, xv.y, xv.z, xv.w};
#pragma unroll
    for (int i = 0; i < 4; ++i)
#pragma unroll
      for (int j = 0; j < 4; ++j)
        ac2[i][j] += wr[i] * xr[j];
  }
  float4 bc0 = *(const float4*)&bc1[cg];
  const float bc0r[4] = {bc0.x, bc0.y, bc0.z, bc0.w};
#pragma unroll
  for (int j = 0; j < 4; ++j) {
    float4 st; float* sv = (float*)&st;
#pragma unroll
    for (int i = 0; i < 4; ++i) sv[i] = fmaxf(ac2[i][j] + bc0r[i], 0.f);
    *(float4*)&Y[(size_t)(p0 + pg + j)*128 + cg] = st;
  }
  __syncthreads();
  for (int i = tid; i < 4096; i += 256) {
    int r = i >> 6, k = i & 63;
    Wt[k][r] = Wc1[(size_t)(64 + r)*64 + k];
  }
  __syncthreads();
  float ac3[4][4] = {{0.f,0.f,0.f,0.f},{0.f,0.f,0.f,0.f},{0.f,0.f,0.f,0.f},{0.f,0.f,0.f,0.f}};
#pragma unroll
  for (int k = 0; k < 64; ++k) {
    float4 wv = *(const float4*)&Wt[k][cg];
    float4 xv = *(const float4*)&Xt[k][pg];
    const float wr[4] = {wv.x, wv.y, wv.z, wv.w};
    const float xr[4] = {xv.x, xv.y, xv.z, xv.w};
#pragma unroll
    for (int i = 0; i < 4; ++i)
#pragma unroll
      for (int j = 0; j < 4; ++j)
        ac3[i][j] += wr[i] * xr[j];
  }
  float4 bc4 = *(const float4*)&bc1[64 + cg];
  const float bc4r[4] = {bc4.x, bc4.y, bc4.z, bc4.w};
#pragma unroll
  for (int j = 0; j < 4; ++j) {
    float4 st; float* sv = (float*)&st;
#pragma unroll
    for (int i = 0; i < 4; ++i) sv[i] = fmaxf(ac3[i][j] + bc4r[i], 0.f);
    *(float4*)&Y[(size_t)(p0 + pg + j)*128 + 64 + cg] = st;
  }
}

// ---------------------------------------------------------------- pool128-gather fused into lin2 (128->128, bf16 out)
// R11 version (measured 57us; three restructures all regressed — do not touch)
__global__ __launch_bounds__(256) void k_lin2p(const float* __restrict__ A,   // act2 (P,128)
                                               const int* __restrict__ idx,
                                               const float* __restrict__ W,
                                               const float* __restrict__ bias,
                                               unsigned short* __restrict__ Y) {
  __shared__ __align__(16) float Wt[64][68];
  __shared__ __align__(16) float Xt[64][68];
  __shared__ int il[1024];
  const int tid = threadIdx.x;
  const int co0 = blockIdx.x * 64;
  const int p0  = blockIdx.y * 64;
  const int cg = (tid & 15) * 4;
  const int pg = (tid >> 4) * 4;
  const int gr = tid >> 2, gk = (tid & 3) * 16;
  const float* Ab = A + (size_t)((p0 >> 11) << 11) * 128;
  *(int4*)&il[tid*4] = *(const int4*)&idx[(size_t)p0*16 + tid*4];
  float acc[4][4] = {{0.f,0.f,0.f,0.f},{0.f,0.f,0.f,0.f},{0.f,0.f,0.f,0.f},{0.f,0.f,0.f,0.f}};
  for (int kt = 0; kt < 128; kt += 64) {
    __syncthreads();
    for (int i = tid; i < 4096; i += 256) {
      int r = i >> 6, k = i & 63;
      Wt[k][r] = W[(size_t)(co0 + r)*128 + kt + k];
    }
    {
      float4 mm[4];
#pragma unroll
      for (int u = 0; u < 4; ++u) mm[u] = make_float4(-INFINITY,-INFINITY,-INFINITY,-INFINITY);
      const int* ir = &il[gr*16];
#pragma unroll
      for (int nb = 0; nb < 16; ++nb) {
        int j = ir[nb];
        const float4* row = (const float4*)&Ab[(size_t)j*128 + kt + gk];
        mm[0] = max4(mm[0], row[0]);
        mm[1] = max4(mm[1], row[1]);
        mm[2] = max4(mm[2], row[2]);
        mm[3] = max4(mm[3], row[3]);
      }
      const float* mf = (const float*)mm;
#pragma unroll
      for (int u = 0; u < 16; ++u) Xt[gk + u][gr] = mf[u];
    }
    __syncthreads();
#pragma unroll
    for (int k = 0; k < 64; ++k) {
      float4 wv = *(const float4*)&Wt[k][cg];
      float4 xv = *(const float4*)&Xt[k][pg];
      const float wr[4] = {wv.x, wv.y, wv.z, wv.w};
      const float xr[4] = {xv.x, xv.y, xv.z, xv.w};
#pragma unroll
      for (int i = 0; i < 4; ++i)
#pragma unroll
        for (int j = 0; j < 4; ++j)
          acc[i][j] += wr[i] * xr[j];
    }
  }
  float4 bv = *(const float4*)&bias[co0 + cg];
  const float br[4] = {bv.x, bv.y, bv.z, bv.w};
#pragma unroll
  for (int j = 0; j < 4; ++j) {
    ushort4 st;
    st.x = f2bf(acc[0][j] + br[0]);
    st.y = f2bf(acc[1][j] + br[1]);
    st.z = f2bf(acc[2][j] + br[2]);
    st.w = f2bf(acc[3][j] + br[3]);
    *(ushort4*)&Y[(size_t)(p0 + pg + j)*128 + co0 + cg] = st;
  }
}

// ---------------------------------------------------------------- c2 (128->1024) bf16 MFMA, fused max (R11 — measured win)
__global__ __launch_bounds__(256) void k_c2max(const unsigned short* __restrict__ X,  // act3b (B*N,128) bf16
                                               const unsigned short* __restrict__ W,  // (1024,128) bf16
                                               float* __restrict__ part) {            // (B,1024,4)
  __shared__ __align__(16) unsigned short Alds[128*136];
  __shared__ float red[128][4];
  const int tid  = threadIdx.x;
  const int wave = tid >> 6, lane = tid & 63;
  const int co0  = blockIdx.x * 128;
  const int p0   = blockIdx.y * 512;
  const int b    = blockIdx.z;
  const unsigned short* Xb = X + ((size_t)b * N_ + p0) * 128;

  for (int i = tid; i < 2048; i += 256) {
    int r = i >> 4, k8 = (i & 15) * 8;
    *(short8*)&Alds[r*136 + k8] = *(const short8*)&W[(size_t)(co0 + r)*128 + k8];
  }

  const int l16 = lane & 15, quad = lane >> 4;
  float mx[8][4];
#pragma unroll
  for (int t = 0; t < 8; ++t)
#pragma unroll
    for (int r = 0; r < 4; ++r) mx[t][r] = -INFINITY;

  for (int sub = 0; sub < 4; ++sub) {
    const unsigned short* Xs = Xb + (size_t)sub * 128 * 128;
    short8 b0[4], b1[4];
#pragma unroll
    for (int k0 = 0; k0 < 4; ++k0) {
      const int kk = k0*32 + quad*8;
      b0[k0] = *(const short8*)&Xs[(size_t)(wave*32 +      l16)*128 + kk];
      b1[k0] = *(const short8*)&Xs[(size_t)(wave*32 + 16 + l16)*128 + kk];
    }
    if (sub == 0) __syncthreads();   // Alds ready (X loads independent)

    f32x4 acc[8][2];
#pragma unroll
    for (int t = 0; t < 8; ++t) { acc[t][0] = (f32x4)0.f; acc[t][1] = (f32x4)0.f; }
#pragma unroll
    for (int k0 = 0; k0 < 4; ++k0) {
      const int kk = k0*32 + quad*8;
#pragma unroll
      for (int t = 0; t < 8; ++t) {
        short8 af = *(const short8*)&Alds[(t*16 + l16)*136 + kk];
        acc[t][0] = __builtin_amdgcn_mfma_f32_16x16x32_bf16(af, b0[k0], acc[t][0], 0, 0, 0);
        acc[t][1] = __builtin_amdgcn_mfma_f32_16x16x32_bf16(af, b1[k0], acc[t][1], 0, 0, 0);
      }
    }
#pragma unroll
    for (int t = 0; t < 8; ++t)
#pragma unroll
      for (int r = 0; r < 4; ++r)
        mx[t][r] = fmaxf(mx[t][r], fmaxf(acc[t][0][r], acc[t][1][r]));
  }

#pragma unroll
  for (int t = 0; t < 8; ++t) {
#pragma unroll
    for (int r = 0; r < 4; ++r) {
      float m = mx[t][r];
      m = fmaxf(m, __shfl_xor(m, 1));
      m = fmaxf(m, __shfl_xor(m, 2));
      m = fmaxf(m, __shfl_xor(m, 4));
      m = fmaxf(m, __shfl_xor(m, 8));
      if (l16 == 0) red[t*16 + quad*4 + r][wave] = m;
    }
  }
  __syncthreads();
  if (tid < 128) {
    float m = fmaxf(fmaxf(red[tid][0], red[tid][1]), fmaxf(red[tid][2], red[tid][3]));
    part[((size_t)b*1024 + co0 + tid)*4 + blockIdx.y] = m;
  }
}

// ---------------------------------------------------------------- R18: c2red fused into m2aW (k_m2aG). g computed per-block
// from part (16KB coalesced, L2-resident; same max/add order -> bit-identical).
__global__ __launch_bounds__(256) void k_m2aG(const float* __restrict__ part,  // (B,1024,4)
                                              const float* __restrict__ bc2,
                                              const float* __restrict__ Wa,
                                              const float* __restrict__ ba,
                                              float* __restrict__ h1) {
  __shared__ __align__(16) float gl[1024];
  const int tid = threadIdx.x;
  const int b   = blockIdx.x >> 5;          // 0..15
  const int oc  = (blockIdx.x & 31) * 16;   // 16 outputs per block
  for (int i = tid; i < 1024; i += 256) {
    const float* p = part + ((size_t)b*1024 + i)*4;
    gl[i] = fmaxf(fmaxf(p[0], p[1]), fmaxf(p[2], p[3])) + bc2[i];
  }
  __syncthreads();
  const int wave = tid >> 6, lane = tid & 63;
  const float4* g4 = (const float4*)gl;
#pragma unroll
  for (int u = 0; u < 4; ++u) {
    const int o = oc + wave*4 + u;
    const float4* wr = (const float4*)(Wa + (size_t)o*1024);
    float a = 0.f;
#pragma unroll
    for (int t = 0; t < 4; ++t) {
      float4 w = wr[lane + t*64], v = g4[lane + t*64];
      a += w.x*v.x + w.y*v.y + w.z*v.z + w.w*v.w;
    }
    a += __shfl_xor(a, 1);  a += __shfl_xor(a, 2);  a += __shfl_xor(a, 4);
    a += __shfl_xor(a, 8);  a += __shfl_xor(a, 16); a += __shfl_xor(a, 32);
    if (lane == 0) h1[(size_t)b*512 + o] = fmaxf(a + ba[o], 0.f);
  }
}

__global__ __launch_bounds__(256) void k_m2bW(const float* __restrict__ h1,
                                              const float* __restrict__ Wb,
                                              const float* __restrict__ bb,
                                              float* __restrict__ h2) {
  __shared__ __align__(16) float hl[512];
  const int tid = threadIdx.x;
  const int b   = blockIdx.x >> 5;
  const int oc  = (blockIdx.x & 31) * 16;
  for (int i = tid; i < 512; i += 256) hl[i] = h1[(size_t)b*512 + i];
  __syncthreads();
  const int wave = tid >> 6, lane = tid & 63;
  const float4* h4 = (const float4*)hl;
#pragma unroll
  for (int u = 0; u < 4; ++u) {
    const int o = oc + wave*4 + u;
    const float4* wr = (const float4*)(Wb + (size_t)o*512);
    float a = 0.f;
#pragma unroll
    for (int t = 0; t < 2; ++t) {
      float4 w = wr[lane + t*64], v = h4[lane + t*64];
      a += w.x*v.x + w.y*v.y + w.z*v.z + w.w*v.w;
    }
    a += __shfl_xor(a, 1);  a += __shfl_xor(a, 2);  a += __shfl_xor(a, 4);
    a += __shfl_xor(a, 8);  a += __shfl_xor(a, 16); a += __shfl_xor(a, 32);
    if (lane == 0) h2[(size_t)b*512 + o] = a + bb[o];
  }
}

__global__ __launch_bounds__(256) void k_embW(const float* __restrict__ h2,
                                              const float* __restrict__ We,
                                              float* __restrict__ out) {
  __shared__ __align__(16) float hl[512];
  const int tid = threadIdx.x;
  const int b   = blockIdx.x >> 3;          // 0..15
  const int oc  = (blockIdx.x & 7) * 16;    // 128 outputs / 8 blocks
  for (int i = tid; i < 512; i += 256) hl[i] = h2[(size_t)b*512 + i];
  __syncthreads();
  const int wave = tid >> 6, lane = tid & 63;
  const float4* h4 = (const float4*)hl;
#pragma unroll
  for (int u = 0; u < 4; ++u) {
    const int o = oc + wave*4 + u;
    const float4* wr = (const float4*)(We + (size_t)o*512);
    float a = 0.f;
#pragma unroll
    for (int t = 0; t < 2; ++t) {
      float4 w = wr[lane + t*64], v = h4[lane + t*64];
      a += w.x*v.x + w.y*v.y + w.z*v.z + w.w*v.w;
    }
    a += __shfl_xor(a, 1);  a += __shfl_xor(a, 2);  a += __shfl_xor(a, 4);
    a += __shfl_xor(a, 8);  a += __shfl_xor(a, 16); a += __shfl_xor(a, 32);
    if (lane == 0) out[(size_t)b*128 + o] = a;
  }
}

// ---------------------------------------------------------------- launch
extern "C" void kernel_launch(void* const* d_in, const int* in_sizes, int n_in,
                              void* d_out, int out_size, void* d_ws, size_t ws_size,
                              hipStream_t stream) {
  const float* pts    = (const float*)d_in[0];
  const float* W_m1a  = (const float*)d_in[1];
  const float* b_m1a  = (const float*)d_in[2];
  const float* W_m1b  = (const float*)d_in[3];
  const float* b_m1b  = (const float*)d_in[4];
  const float* W_m1c  = (const float*)d_in[5];
  const float* b_m1c  = (const float*)d_in[6];
  const float* W_lin1 = (const float*)d_in[7];
  const float* b_lin1 = (const float*)d_in[8];
  const float* W_c1   = (const float*)d_in[9];
  const float* b_c1   = (const float*)d_in[10];
  const float* W_lin2 = (const float*)d_in[11];
  const float* b_lin2 = (const float*)d_in[12];
  const float* W_c2   = (const float*)d_in[13];
  const float* b_c2   = (const float*)d_in[14];
  const float* W_m2a  = (const float*)d_in[15];
  const float* b_m2a  = (const float*)d_in[16];
  const float* W_m2b  = (const float*)d_in[17];
  const float* b_m2b  = (const float*)d_in[18];
  const float* W_emb  = (const float*)d_in[19];
  float* out = (float*)d_out;

  char* ws = (char*)d_ws;
  const size_t MB = 1024*1024;
  // liveness-overlapped layout (peak 35 MB):
  float4* pts4 = (float4*)(ws + 0);                        // 512 KB, dead after mergecov
  unsigned short* wc2b = (unsigned short*)(ws + 512*1024); // 256 KB, live till c2max
  int*    idx  = (int*)  (ws + 1*MB);                      // 2 MB, live till lin2p
  u64*    pk   = (u64*)  (ws + 3*MB);                      // 16 MB keys, dead after mergecov
  float*  act0 = (float*)(ws + 19*MB);                     // 8 MB (P,64)
  float*  act1 = (float*)(ws + 3*MB);                      // 8 MB (P,64) — pk dead
  float*  act2 = (float*)(ws + 19*MB);                     // 16 MB (P,128) — act0 dead
  unsigned short* act3b = (unsigned short*)(ws + 3*MB);    // 8 MB bf16 (P,128) — act1 dead
  float*  part = (float*)(ws + 12*MB);                     // 256 KB (B,1024,4)
  float*  h1   = (float*)(ws + 0);                         // 32 KB (pts4 dead by tail)
  float*  h2   = (float*)(ws + 64*1024);                   // 32 KB

  k_prep2   <<<256, 256, 0, stream>>>(pts, W_c2, pts4, wc2b);
  k_knn4    <<<dim3(128, 4), 256, 0, stream>>>(pts4, pk);
  k_mergecov<<<128, 256, 0, stream>>>(pk, pts4, W_m1a, b_m1a, idx, act0);
  k_m1bc    <<<512, 256, 0, stream>>>(act0, W_m1b, b_m1b, W_m1c, b_m1c, act1);
  k_lin1c1  <<<512, 256, 0, stream>>>(act1, idx, W_lin1, b_lin1, W_c1, b_c1, act2);
  k_lin2p   <<<dim3(2,512), 256, 0, stream>>>(act2, idx, W_lin2, b_lin2, act3b);
  k_c2max   <<<dim3(8,4,16), 256, 0, stream>>>(act3b, wc2b, part);
  k_m2aG    <<<512, 256, 0, stream>>>(part, b_c2, W_m2a, b_m2a, h1);
  k_m2bW    <<<512, 256, 0, stream>>>(h1, W_m2b, b_m2b, h2);
  k_embW    <<<128, 256, 0, stream>>>(h2, W_emb, out);
}

// Round 17
// 344.852 us; speedup vs baseline: 1.1414x; 1.1414x over previous
//
#include <hip/hip_runtime.h>
#include <math.h>

#define N_   2048
#define NPTS 32768   // B*N = 16*2048

typedef __attribute__((ext_vector_type(8))) short short8;   // 8 bf16 (4 VGPRs)
typedef __attribute__((ext_vector_type(4))) float f32x4;
typedef unsigned long long u64;

__device__ __forceinline__ unsigned short f2bf(float f) {   // RTNE
  unsigned int u = __float_as_uint(f);
  return (unsigned short)((u + 0x7fffu + ((u >> 16) & 1u)) >> 16);
}
__device__ __forceinline__ float4 max4(float4 a, float4 b) {
  return make_float4(fmaxf(a.x,b.x), fmaxf(a.y,b.y), fmaxf(a.z,b.z), fmaxf(a.w,b.w));
}

// ---------------------------------------------------------------- prep (x,y,z,|p|^2) + W_c2->bf16
__global__ __launch_bounds__(256) void k_prep2(const float* __restrict__ pts,
                                               const float* __restrict__ Wc2,
                                               float4* __restrict__ pts4,
                                               unsigned short* __restrict__ wb) {
  if (blockIdx.x < 128) {
    int P = blockIdx.x * 256 + threadIdx.x;
    float x = pts[P*3+0], y = pts[P*3+1], z = pts[P*3+2];
    float xx = __fadd_rn(__fadd_rn(__fmul_rn(x,x), __fmul_rn(y,y)), __fmul_rn(z,z));
    pts4[P] = make_float4(x, y, z, xx);
  } else {
    int i = ((blockIdx.x - 128) * 256 + threadIdx.x) * 4;
    float4 w = *(const float4*)&Wc2[i];
    *(ushort4*)&wb[i] = make_ushort4(f2bf(w.x), f2bf(w.y), f2bf(w.z), f2bf(w.w));
  }
}

// ---------------------------------------------------------------- knn (R9 — measured 106 us local optimum)
#define KCAP 32
__global__ __launch_bounds__(256) void k_knn4(const float4* __restrict__ pts4,
                                              u64* __restrict__ pk) {
  __shared__ float4 cand[512];
  __shared__ u64 ring[KCAP+1][256];   // +1 guard row for prefetch at s+1
  const int tid = threadIdx.x;
  const int qg  = blockIdx.x;      // 0..127: query group of 256
  const int ch  = blockIdx.y;      // 0..3:   candidate chunk
  const int P   = qg * 256 + tid;  // global query point
  const float4* base = pts4 + ((P >> 11) << 11);
  const int j0 = ch << 9;
  for (int i = tid; i < 512; i += 256) cand[i] = base[j0 + i];
  const float4 q = base[P & (N_-1)];
  __syncthreads();

  u64 K[16];
#pragma unroll
  for (int t = 0; t < 16; ++t) K[t] = 0ull;   // 0 < any real key -> -inf sentinel
  u64 kmin = 0ull;
  int cnt = 0;

#define FLUSH4() do { \
    int s = 0; \
    u64 fk_next = ring[0][tid]; \
    while (__any(s < cnt)) { \
      u64 fk = (s < cnt) ? fk_next : 0ull; \
      fk_next = ring[s+1][tid]; \
      if (fk > kmin) { \
        _Pragma("unroll") \
        for (int t = 15; t > 0; --t) { \
          if (K[t] < fk) K[t] = (K[t-1] < fk) ? K[t-1] : fk; \
        } \
        if (K[0] < fk) K[0] = fk; \
        kmin = K[15]; \
      } \
      ++s; \
    } \
    cnt = 0; \
  } while (0)

  for (int jj = 0; jj < 512; jj += 4) {
    if (__any(cnt > KCAP - 4)) FLUSH4();
#pragma unroll
    for (int u = 0; u < 4; ++u) {
      float4 c = cand[jj + u];
      float inner = __fadd_rn(__fadd_rn(__fmul_rn(q.x,c.x), __fmul_rn(q.y,c.y)),
                              __fmul_rn(q.z,c.z));
      float dj = __fsub_rn(__fsub_rn(__fmul_rn(2.f, inner), q.w), c.w);
      unsigned int du = __float_as_uint(dj);
      unsigned int kd = du ^ (((unsigned int)((int)du >> 31)) | 0x80000000u);
      u64 key = ((u64)kd << 32) | (unsigned int)(~(j0 + jj + u));
      if (key > kmin) { ring[cnt][tid] = key; ++cnt; }
    }
  }
  FLUSH4();
#undef FLUSH4
#pragma unroll
  for (int t = 0; t < 16; ++t)
    pk[((size_t)P*4 + ch)*16 + t] = K[t];
}

// ---------------------------------------------------------------- merge four sorted-16 lists + local_cov + m1a
// (probe reverted; original 128x256 config — measured ~13us via R18 arithmetic)
__device__ __forceinline__ void kmerge16(const u64* a, const u64* b, u64* m) {
#pragma unroll
  for (int t = 0; t < 16; ++t) m[t] = (a[t] >= b[15-t]) ? a[t] : b[15-t];
#pragma unroll
  for (int dd = 8; dd >= 1; dd >>= 1)
#pragma unroll
    for (int i = 0; i < 16; ++i)
      if ((i & dd) == 0) {
        int j = i + dd;
        if (m[i] < m[j]) { u64 t_ = m[i]; m[i] = m[j]; m[j] = t_; }
      }
}

__global__ __launch_bounds__(256) void k_mergecov(const u64* __restrict__ pk,
                                                  const float4* __restrict__ pts4,
                                                  const float* __restrict__ W,
                                                  const float* __restrict__ bias,
                                                  int* __restrict__ idx,
                                                  float* __restrict__ act0) {
  __shared__ float Wl[64*12];
  __shared__ float bl[64];
  const int tid = threadIdx.x;
  for (int i = tid; i < 768; i += 256) Wl[i] = W[i];
  if (tid < 64) bl[tid] = bias[tid];
  __syncthreads();

  int P = blockIdx.x * 256 + tid;
  const u64* row = pk + (size_t)P * 64;
  u64 L0[16], L1[16], A[16], B[16], M[16];
#pragma unroll
  for (int t = 0; t < 16; ++t) { L0[t] = row[t]; L1[t] = row[16+t]; }
  kmerge16(L0, L1, A);
#pragma unroll
  for (int t = 0; t < 16; ++t) { L0[t] = row[32+t]; L1[t] = row[48+t]; }
  kmerge16(L0, L1, B);
  kmerge16(A, B, M);
#pragma unroll
  for (int t = 0; t < 16; ++t)
    idx[(size_t)P*16 + t] = (int)(~(unsigned int)(M[t] & 0xFFFFFFFFull));

  const int j0 = (int)(~(unsigned int)(M[0] & 0xFFFFFFFFull));
  const int j1 = (int)(~(unsigned int)(M[1] & 0xFFFFFFFFull));
  const float4* base = pts4 + ((P >> 11) << 11);
  float4 p  = base[P & (N_-1)];
  float4 n0 = base[j0];
  float4 n1 = base[j1];
  float f[12];
  f[0]=p.x; f[1]=p.y; f[2]=p.z;
  f[3]=n0.x*n1.x; f[4]=n0.x*n1.y; f[5]=n0.x*n1.z;
  f[6]=n0.y*n1.x; f[7]=n0.y*n1.y; f[8]=n0.y*n1.z;
  f[9]=n0.z*n1.x; f[10]=n0.z*n1.y; f[11]=n0.z*n1.z;
  float* out = act0 + (size_t)P*64;
  for (int o4 = 0; o4 < 64; o4 += 4) {
    float4 v; float* vv = (float*)&v;
#pragma unroll
    for (int u = 0; u < 4; ++u) {
      int o = o4 + u;
      float acc = bl[o];
#pragma unroll
      for (int ci = 0; ci < 12; ++ci) acc += Wl[o*12+ci] * f[ci];
      vv[u] = fmaxf(acc, 0.f);
    }
    *(float4*)&out[o4] = v;
  }
}

// ---------------------------------------------------------------- fused m1b+m1c (64->64 relu, 64->64 relu)
__global__ __launch_bounds__(256) void k_m1bc(const float* __restrict__ X,
                                              const float* __restrict__ W1, const float* __restrict__ b1,
                                              const float* __restrict__ W2, const float* __restrict__ b2,
                                              float* __restrict__ Y) {
  __shared__ __align__(16) float Wt[64][68];
  __shared__ __align__(16) float Xt[64][68];
  const int tid = threadIdx.x;
  const int p0  = blockIdx.x * 64;
  const int cg = (tid & 15) * 4;
  const int pg = (tid >> 4) * 4;
  for (int i = tid; i < 4096; i += 256) {
    int r = i >> 6, k = i & 63;
    Wt[k][r] = W1[(size_t)r*64 + k];
    Xt[k][r] = X[(size_t)(p0 + r)*64 + k];
  }
  __syncthreads();
  float acc[4][4] = {{0.f,0.f,0.f,0.f},{0.f,0.f,0.f,0.f},{0.f,0.f,0.f,0.f},{0.f,0.f,0.f,0.f}};
#pragma unroll
  for (int k = 0; k < 64; ++k) {
    float4 wv = *(const float4*)&Wt[k][cg];
    float4 xv = *(const float4*)&Xt[k][pg];
    const float wr[4] = {wv.x, wv.y, wv.z, wv.w};
    const float xr[4] = {xv.x, xv.y, xv.z, xv.w};
#pragma unroll
    for (int i = 0; i < 4; ++i)
#pragma unroll
      for (int j = 0; j < 4; ++j)
        acc[i][j] += wr[i] * xr[j];
  }
  __syncthreads();
  float4 bv1 = *(const float4*)&b1[cg];
  const float br1[4] = {bv1.x, bv1.y, bv1.z, bv1.w};
#pragma unroll
  for (int i = 0; i < 4; ++i) {
    float4 v;
    v.x = fmaxf(acc[i][0] + br1[i], 0.f);
    v.y = fmaxf(acc[i][1] + br1[i], 0.f);
    v.z = fmaxf(acc[i][2] + br1[i], 0.f);
    v.w = fmaxf(acc[i][3] + br1[i], 0.f);
    *(float4*)&Xt[cg + i][pg] = v;
  }
  for (int i = tid; i < 4096; i += 256) {
    int r = i >> 6, k = i & 63;
    Wt[k][r] = W2[(size_t)r*64 + k];
  }
  __syncthreads();
  float ac2[4][4] = {{0.f,0.f,0.f,0.f},{0.f,0.f,0.f,0.f},{0.f,0.f,0.f,0.f},{0.f,0.f,0.f,0.f}};
#pragma unroll
  for (int k = 0; k < 64; ++k) {
    float4 wv = *(const float4*)&Wt[k][cg];
    float4 xv = *(const float4*)&Xt[k][pg];
    const float wr[4] = {wv.x, wv.y, wv.z, wv.w};
    const float xr[4] = {xv.x, xv.y, xv.z, xv.w};
#pragma unroll
    for (int i = 0; i < 4; ++i)
#pragma unroll
      for (int j = 0; j < 4; ++j)
        ac2[i][j] += wr[i] * xr[j];
  }
  float4 bv2 = *(const float4*)&b2[cg];
  const float br2[4] = {bv2.x, bv2.y, bv2.z, bv2.w};
#pragma unroll
  for (int j = 0; j < 4; ++j) {
    float4 st; float* sv = (float*)&st;
#pragma unroll
    for (int i = 0; i < 4; ++i) sv[i] = fmaxf(ac2[i][j] + br2[i], 0.f);
    *(float4*)&Y[(size_t)(p0 + pg + j)*64 + cg] = st;
  }
}

// ---------------------------------------------------------------- fused pool64 -> lin1 -> relu(c1): act1 -> act2 (P,128)
// R19: 512 threads/block, same 64-pt tile. Occupancy 2->4 waves/SIMD
// (lin1c1 was the only latency-bound gather kernel at 2 waves/SIMD; lin2p
// runs 4 and sustains more gather bytes in similar time). Same nb/k order
// per output -> bit-identical.
__global__ __launch_bounds__(512) void k_lin1c1(const float* __restrict__ A,   // act1 (P,64)
                                                const int* __restrict__ idx,
                                                const float* __restrict__ Wl1, const float* __restrict__ bl1,
                                                const float* __restrict__ Wc1, const float* __restrict__ bc1,
                                                float* __restrict__ Y) {       // act2 (P,128)
  __shared__ __align__(16) float Wt[64][68];
  __shared__ __align__(16) float Xt[64][68];
  __shared__ int il[1024];
  const int tid = threadIdx.x;            // 0..511
  const int p0  = blockIdx.x * 64;
  const int cg = (tid & 15) * 4;          // 16 col groups x 4
  const int pg = (tid >> 4) * 2;          // 32 pt groups x 2
  const int gr = tid >> 3;                // 64 points
  const int gk = (tid & 7) * 8;           // 8 channels each
  const float* Ab = A + (size_t)((p0 >> 11) << 11) * 64;
  *(int2*)&il[tid*2] = *(const int2*)&idx[(size_t)p0*16 + tid*2];
  for (int i = tid; i < 4096; i += 512) {
    int r = i >> 6, k = i & 63;
    Wt[k][r] = Wl1[(size_t)r*64 + k];
  }
  __syncthreads();
  {
    float4 mm[2];
    mm[0] = make_float4(-INFINITY,-INFINITY,-INFINITY,-INFINITY);
    mm[1] = mm[0];
    const int* ir = &il[gr*16];
#pragma unroll
    for (int nb = 0; nb < 16; ++nb) {
      int j = ir[nb];
      const float4* row = (const float4*)&Ab[(size_t)j*64 + gk];
      mm[0] = max4(mm[0], row[0]);
      mm[1] = max4(mm[1], row[1]);
    }
    const float* mf = (const float*)mm;
#pragma unroll
    for (int u = 0; u < 8; ++u) Xt[gk + u][gr] = mf[u];
  }
  __syncthreads();
  float acc[4][2] = {{0.f,0.f},{0.f,0.f},{0.f,0.f},{0.f,0.f}};
#pragma unroll
  for (int k = 0; k < 64; ++k) {
    float4 wv = *(const float4*)&Wt[k][cg];
    float2 xv = *(const float2*)&Xt[k][pg];
    const float wr[4] = {wv.x, wv.y, wv.z, wv.w};
    const float xr[2] = {xv.x, xv.y};
#pragma unroll
    for (int i = 0; i < 4; ++i)
#pragma unroll
      for (int j = 0; j < 2; ++j)
        acc[i][j] += wr[i] * xr[j];
  }
  __syncthreads();
  float4 bv = *(const float4*)&bl1[cg];
  const float br[4] = {bv.x, bv.y, bv.z, bv.w};
#pragma unroll
  for (int i = 0; i < 4; ++i) {
    float2 v;
    v.x = acc[i][0] + br[i];
    v.y = acc[i][1] + br[i];
    *(float2*)&Xt[cg + i][pg] = v;
  }
  for (int i = tid; i < 4096; i += 512) {
    int r = i >> 6, k = i & 63;
    Wt[k][r] = Wc1[(size_t)r*64 + k];
  }
  __syncthreads();
  float ac2[4][2] = {{0.f,0.f},{0.f,0.f},{0.f,0.f},{0.f,0.f}};
#pragma unroll
  for (int k = 0; k < 64; ++k) {
    float4 wv = *(const float4*)&Wt[k][cg];
    float2 xv = *(const float2*)&Xt[k][pg];
    const float wr[4] = {wv.x, wv.y, wv.z, wv.w};
    const float xr[2] = {xv.x, xv.y};
#pragma unroll
    for (int i = 0; i < 4; ++i)
#pragma unroll
      for (int j = 0; j < 2; ++j)
        ac2[i][j] += wr[i] * xr[j];
  }
  float4 bc0 = *(const float4*)&bc1[cg];
  const float bc0r[4] = {bc0.x, bc0.y, bc0.z, bc0.w};
#pragma unroll
  for (int j = 0; j < 2; ++j) {
    float4 st; float* sv = (float*)&st;
#pragma unroll
    for (int i = 0; i < 4; ++i) sv[i] = fmaxf(ac2[i][j] + bc0r[i], 0.f);
    *(float4*)&Y[(size_t)(p0 + pg + j)*128 + cg] = st;
  }
  __syncthreads();
  for (int i = tid; i < 4096; i += 512) {
    int r = i >> 6, k = i & 63;
    Wt[k][r] = Wc1[(size_t)(64 + r)*64 + k];
  }
  __syncthreads();
  float ac3[4][2] = {{0.f,0.f},{0.f,0.f},{0.f,0.f},{0.f,0.f}};
#pragma unroll
  for (int k = 0; k < 64; ++k) {
    float4 wv = *(const float4*)&Wt[k][cg];
    float2 xv = *(const float2*)&Xt[k][pg];
    const float wr[4] = {wv.x, wv.y, wv.z, wv.w};
    const float xr[2] = {xv.x, xv.y};
#pragma unroll
    for (int i = 0; i < 4; ++i)
#pragma unroll
      for (int j = 0; j < 2; ++j)
        ac3[i][j] += wr[i] * xr[j];
  }
  float4 bc4 = *(const float4*)&bc1[64 + cg];
  const float bc4r[4] = {bc4.x, bc4.y, bc4.z, bc4.w};
#pragma unroll
  for (int j = 0; j < 2; ++j) {
    float4 st; float* sv = (float*)&st;
#pragma unroll
    for (int i = 0; i < 4; ++i) sv[i] = fmaxf(ac3[i][j] + bc4r[i], 0.f);
    *(float4*)&Y[(size_t)(p0 + pg + j)*128 + 64 + cg] = st;
  }
}

// ---------------------------------------------------------------- pool128-gather fused into lin2 (128->128, bf16 out)
// R11 version (measured 57us; three restructures all regressed — do not touch)
__global__ __launch_bounds__(256) void k_lin2p(const float* __restrict__ A,   // act2 (P,128)
                                               const int* __restrict__ idx,
                                               const float* __restrict__ W,
                                               const float* __restrict__ bias,
                                               unsigned short* __restrict__ Y) {
  __shared__ __align__(16) float Wt[64][68];
  __shared__ __align__(16) float Xt[64][68];
  __shared__ int il[1024];
  const int tid = threadIdx.x;
  const int co0 = blockIdx.x * 64;
  const int p0  = blockIdx.y * 64;
  const int cg = (tid & 15) * 4;
  const int pg = (tid >> 4) * 4;
  const int gr = tid >> 2, gk = (tid & 3) * 16;
  const float* Ab = A + (size_t)((p0 >> 11) << 11) * 128;
  *(int4*)&il[tid*4] = *(const int4*)&idx[(size_t)p0*16 + tid*4];
  float acc[4][4] = {{0.f,0.f,0.f,0.f},{0.f,0.f,0.f,0.f},{0.f,0.f,0.f,0.f},{0.f,0.f,0.f,0.f}};
  for (int kt = 0; kt < 128; kt += 64) {
    __syncthreads();
    for (int i = tid; i < 4096; i += 256) {
      int r = i >> 6, k = i & 63;
      Wt[k][r] = W[(size_t)(co0 + r)*128 + kt + k];
    }
    {
      float4 mm[4];
#pragma unroll
      for (int u = 0; u < 4; ++u) mm[u] = make_float4(-INFINITY,-INFINITY,-INFINITY,-INFINITY);
      const int* ir = &il[gr*16];
#pragma unroll
      for (int nb = 0; nb < 16; ++nb) {
        int j = ir[nb];
        const float4* row = (const float4*)&Ab[(size_t)j*128 + kt + gk];
        mm[0] = max4(mm[0], row[0]);
        mm[1] = max4(mm[1], row[1]);
        mm[2] = max4(mm[2], row[2]);
        mm[3] = max4(mm[3], row[3]);
      }
      const float* mf = (const float*)mm;
#pragma unroll
      for (int u = 0; u < 16; ++u) Xt[gk + u][gr] = mf[u];
    }
    __syncthreads();
#pragma unroll
    for (int k = 0; k < 64; ++k) {
      float4 wv = *(const float4*)&Wt[k][cg];
      float4 xv = *(const float4*)&Xt[k][pg];
      const float wr[4] = {wv.x, wv.y, wv.z, wv.w};
      const float xr[4] = {xv.x, xv.y, xv.z, xv.w};
#pragma unroll
      for (int i = 0; i < 4; ++i)
#pragma unroll
        for (int j = 0; j < 4; ++j)
          acc[i][j] += wr[i] * xr[j];
    }
  }
  float4 bv = *(const float4*)&bias[co0 + cg];
  const float br[4] = {bv.x, bv.y, bv.z, bv.w};
#pragma unroll
  for (int j = 0; j < 4; ++j) {
    ushort4 st;
    st.x = f2bf(acc[0][j] + br[0]);
    st.y = f2bf(acc[1][j] + br[1]);
    st.z = f2bf(acc[2][j] + br[2]);
    st.w = f2bf(acc[3][j] + br[3]);
    *(ushort4*)&Y[(size_t)(p0 + pg + j)*128 + co0 + cg] = st;
  }
}

// ---------------------------------------------------------------- c2 (128->1024) bf16 MFMA, fused max (R11 — measured win)
__global__ __launch_bounds__(256) void k_c2max(const unsigned short* __restrict__ X,  // act3b (B*N,128) bf16
                                               const unsigned short* __restrict__ W,  // (1024,128) bf16
                                               float* __restrict__ part) {            // (B,1024,4)
  __shared__ __align__(16) unsigned short Alds[128*136];
  __shared__ float red[128][4];
  const int tid  = threadIdx.x;
  const int wave = tid >> 6, lane = tid & 63;
  const int co0  = blockIdx.x * 128;
  const int p0   = blockIdx.y * 512;
  const int b    = blockIdx.z;
  const unsigned short* Xb = X + ((size_t)b * N_ + p0) * 128;

  for (int i = tid; i < 2048; i += 256) {
    int r = i >> 4, k8 = (i & 15) * 8;
    *(short8*)&Alds[r*136 + k8] = *(const short8*)&W[(size_t)(co0 + r)*128 + k8];
  }

  const int l16 = lane & 15, quad = lane >> 4;
  float mx[8][4];
#pragma unroll
  for (int t = 0; t < 8; ++t)
#pragma unroll
    for (int r = 0; r < 4; ++r) mx[t][r] = -INFINITY;

  for (int sub = 0; sub < 4; ++sub) {
    const unsigned short* Xs = Xb + (size_t)sub * 128 * 128;
    short8 b0[4], b1[4];
#pragma unroll
    for (int k0 = 0; k0 < 4; ++k0) {
      const int kk = k0*32 + quad*8;
      b0[k0] = *(const short8*)&Xs[(size_t)(wave*32 +      l16)*128 + kk];
      b1[k0] = *(const short8*)&Xs[(size_t)(wave*32 + 16 + l16)*128 + kk];
    }
    if (sub == 0) __syncthreads();   // Alds ready (X loads independent)

    f32x4 acc[8][2];
#pragma unroll
    for (int t = 0; t < 8; ++t) { acc[t][0] = (f32x4)0.f; acc[t][1] = (f32x4)0.f; }
#pragma unroll
    for (int k0 = 0; k0 < 4; ++k0) {
      const int kk = k0*32 + quad*8;
#pragma unroll
      for (int t = 0; t < 8; ++t) {
        short8 af = *(const short8*)&Alds[(t*16 + l16)*136 + kk];
        acc[t][0] = __builtin_amdgcn_mfma_f32_16x16x32_bf16(af, b0[k0], acc[t][0], 0, 0, 0);
        acc[t][1] = __builtin_amdgcn_mfma_f32_16x16x32_bf16(af, b1[k0], acc[t][1], 0, 0, 0);
      }
    }
#pragma unroll
    for (int t = 0; t < 8; ++t)
#pragma unroll
      for (int r = 0; r < 4; ++r)
        mx[t][r] = fmaxf(mx[t][r], fmaxf(acc[t][0][r], acc[t][1][r]));
  }

#pragma unroll
  for (int t = 0; t < 8; ++t) {
#pragma unroll
    for (int r = 0; r < 4; ++r) {
      float m = mx[t][r];
      m = fmaxf(m, __shfl_xor(m, 1));
      m = fmaxf(m, __shfl_xor(m, 2));
      m = fmaxf(m, __shfl_xor(m, 4));
      m = fmaxf(m, __shfl_xor(m, 8));
      if (l16 == 0) red[t*16 + quad*4 + r][wave] = m;
    }
  }
  __syncthreads();
  if (tid < 128) {
    float m = fmaxf(fmaxf(red[tid][0], red[tid][1]), fmaxf(red[tid][2], red[tid][3]));
    part[((size_t)b*1024 + co0 + tid)*4 + blockIdx.y] = m;
  }
}

// ---------------------------------------------------------------- R18: c2red fused into m2aW (kept — ~+3-5us)
__global__ __launch_bounds__(256) void k_m2aG(const float* __restrict__ part,  // (B,1024,4)
                                              const float* __restrict__ bc2,
                                              const float* __restrict__ Wa,
                                              const float* __restrict__ ba,
                                              float* __restrict__ h1) {
  __shared__ __align__(16) float gl[1024];
  const int tid = threadIdx.x;
  const int b   = blockIdx.x >> 5;          // 0..15
  const int oc  = (blockIdx.x & 31) * 16;   // 16 outputs per block
  for (int i = tid; i < 1024; i += 256) {
    const float* p = part + ((size_t)b*1024 + i)*4;
    gl[i] = fmaxf(fmaxf(p[0], p[1]), fmaxf(p[2], p[3])) + bc2[i];
  }
  __syncthreads();
  const int wave = tid >> 6, lane = tid & 63;
  const float4* g4 = (const float4*)gl;
#pragma unroll
  for (int u = 0; u < 4; ++u) {
    const int o = oc + wave*4 + u;
    const float4* wr = (const float4*)(Wa + (size_t)o*1024);
    float a = 0.f;
#pragma unroll
    for (int t = 0; t < 4; ++t) {
      float4 w = wr[lane + t*64], v = g4[lane + t*64];
      a += w.x*v.x + w.y*v.y + w.z*v.z + w.w*v.w;
    }
    a += __shfl_xor(a, 1);  a += __shfl_xor(a, 2);  a += __shfl_xor(a, 4);
    a += __shfl_xor(a, 8);  a += __shfl_xor(a, 16); a += __shfl_xor(a, 32);
    if (lane == 0) h1[(size_t)b*512 + o] = fmaxf(a + ba[o], 0.f);
  }
}

__global__ __launch_bounds__(256) void k_m2bW(const float* __restrict__ h1,
                                              const float* __restrict__ Wb,
                                              const float* __restrict__ bb,
                                              float* __restrict__ h2) {
  __shared__ __align__(16) float hl[512];
  const int tid = threadIdx.x;
  const int b   = blockIdx.x >> 5;
  const int oc  = (blockIdx.x & 31) * 16;
  for (int i = tid; i < 512; i += 256) hl[i] = h1[(size_t)b*512 + i];
  __syncthreads();
  const int wave = tid >> 6, lane = tid & 63;
  const float4* h4 = (const float4*)hl;
#pragma unroll
  for (int u = 0; u < 4; ++u) {
    const int o = oc + wave*4 + u;
    const float4* wr = (const float4*)(Wb + (size_t)o*512);
    float a = 0.f;
#pragma unroll
    for (int t = 0; t < 2; ++t) {
      float4 w = wr[lane + t*64], v = h4[lane + t*64];
      a += w.x*v.x + w.y*v.y + w.z*v.z + w.w*v.w;
    }
    a += __shfl_xor(a, 1);  a += __shfl_xor(a, 2);  a += __shfl_xor(a, 4);
    a += __shfl_xor(a, 8);  a += __shfl_xor(a, 16); a += __shfl_xor(a, 32);
    if (lane == 0) h2[(size_t)b*512 + o] = a + bb[o];
  }
}

__global__ __launch_bounds__(256) void k_embW(const float* __restrict__ h2,
                                              const float* __restrict__ We,
                                              float* __restrict__ out) {
  __shared__ __align__(16) float hl[512];
  const int tid = threadIdx.x;
  const int b   = blockIdx.x >> 3;          // 0..15
  const int oc  = (blockIdx.x & 7) * 16;    // 128 outputs / 8 blocks
  for (int i = tid; i < 512; i += 256) hl[i] = h2[(size_t)b*512 + i];
  __syncthreads();
  const int wave = tid >> 6, lane = tid & 63;
  const float4* h4 = (const float4*)hl;
#pragma unroll
  for (int u = 0; u < 4; ++u) {
    const int o = oc + wave*4 + u;
    const float4* wr = (const float4*)(We + (size_t)o*512);
    float a = 0.f;
#pragma unroll
    for (int t = 0; t < 2; ++t) {
      float4 w = wr[lane + t*64], v = h4[lane + t*64];
      a += w.x*v.x + w.y*v.y + w.z*v.z + w.w*v.w;
    }
    a += __shfl_xor(a, 1);  a += __shfl_xor(a, 2);  a += __shfl_xor(a, 4);
    a += __shfl_xor(a, 8);  a += __shfl_xor(a, 16); a += __shfl_xor(a, 32);
    if (lane == 0) out[(size_t)b*128 + o] = a;
  }
}

// ---------------------------------------------------------------- launch
extern "C" void kernel_launch(void* const* d_in, const int* in_sizes, int n_in,
                              void* d_out, int out_size, void* d_ws, size_t ws_size,
                              hipStream_t stream) {
  const float* pts    = (const float*)d_in[0];
  const float* W_m1a  = (const float*)d_in[1];
  const float* b_m1a  = (const float*)d_in[2];
  const float* W_m1b  = (const float*)d_in[3];
  const float* b_m1b  = (const float*)d_in[4];
  const float* W_m1c  = (const float*)d_in[5];
  const float* b_m1c  = (const float*)d_in[6];
  const float* W_lin1 = (const float*)d_in[7];
  const float* b_lin1 = (const float*)d_in[8];
  const float* W_c1   = (const float*)d_in[9];
  const float* b_c1   = (const float*)d_in[10];
  const float* W_lin2 = (const float*)d_in[11];
  const float* b_lin2 = (const float*)d_in[12];
  const float* W_c2   = (const float*)d_in[13];
  const float* b_c2   = (const float*)d_in[14];
  const float* W_m2a  = (const float*)d_in[15];
  const float* b_m2a  = (const float*)d_in[16];
  const float* W_m2b  = (const float*)d_in[17];
  const float* b_m2b  = (const float*)d_in[18];
  const float* W_emb  = (const float*)d_in[19];
  float* out = (float*)d_out;

  char* ws = (char*)d_ws;
  const size_t MB = 1024*1024;
  // liveness-overlapped layout (peak 35 MB):
  float4* pts4 = (float4*)(ws + 0);                        // 512 KB, dead after mergecov
  unsigned short* wc2b = (unsigned short*)(ws + 512*1024); // 256 KB, live till c2max
  int*    idx  = (int*)  (ws + 1*MB);                      // 2 MB, live till lin2p
  u64*    pk   = (u64*)  (ws + 3*MB);                      // 16 MB keys, dead after mergecov
  float*  act0 = (float*)(ws + 19*MB);                     // 8 MB (P,64)
  float*  act1 = (float*)(ws + 3*MB);                      // 8 MB (P,64) — pk dead
  float*  act2 = (float*)(ws + 19*MB);                     // 16 MB (P,128) — act0 dead
  unsigned short* act3b = (unsigned short*)(ws + 3*MB);    // 8 MB bf16 (P,128) — act1 dead
  float*  part = (float*)(ws + 12*MB);                     // 256 KB (B,1024,4)
  float*  h1   = (float*)(ws + 0);                         // 32 KB (pts4 dead by tail)
  float*  h2   = (float*)(ws + 64*1024);                   // 32 KB

  k_prep2   <<<256, 256, 0, stream>>>(pts, W_c2, pts4, wc2b);
  k_knn4    <<<dim3(128, 4), 256, 0, stream>>>(pts4, pk);
  k_mergecov<<<128, 256, 0, stream>>>(pk, pts4, W_m1a, b_m1a, idx, act0);
  k_m1bc    <<<512, 256, 0, stream>>>(act0, W_m1b, b_m1b, W_m1c, b_m1c, act1);
  k_lin1c1  <<<512, 512, 0, stream>>>(act1, idx, W_lin1, b_lin1, W_c1, b_c1, act2);
  k_lin2p   <<<dim3(2,512), 256, 0, stream>>>(act2, idx, W_lin2, b_lin2, act3b);
  k_c2max   <<<dim3(8,4,16), 256, 0, stream>>>(act3b, wc2b, part);
  k_m2aG    <<<512, 256, 0, stream>>>(part, b_c2, W_m2a, b_m2a, h1);
  k_m2bW    <<<512, 256, 0, stream>>>(h1, W_m2b, b_m2b, h2);
  k_embW    <<<128, 256, 0, stream>>>(h2, W_emb, out);
}

// Round 19
// 338.700 us; speedup vs baseline: 1.1622x; 1.0182x over previous
//
#include <hip/hip_runtime.h>
#include <math.h>

#define N_   2048
#define NPTS 32768   // B*N = 16*2048

typedef __attribute__((ext_vector_type(8))) short short8;   // 8 bf16 (4 VGPRs)
typedef __attribute__((ext_vector_type(4))) float f32x4;
typedef unsigned long long u64;

__device__ __forceinline__ unsigned short f2bf(float f) {   // RTNE
  unsigned int u = __float_as_uint(f);
  return (unsigned short)((u + 0x7fffu + ((u >> 16) & 1u)) >> 16);
}
__device__ __forceinline__ float4 max4(float4 a, float4 b) {
  return make_float4(fmaxf(a.x,b.x), fmaxf(a.y,b.y), fmaxf(a.z,b.z), fmaxf(a.w,b.w));
}

// ---------------------------------------------------------------- prep (x,y,z,|p|^2) + W_c2->bf16
__global__ __launch_bounds__(256) void k_prep2(const float* __restrict__ pts,
                                               const float* __restrict__ Wc2,
                                               float4* __restrict__ pts4,
                                               unsigned short* __restrict__ wb) {
  if (blockIdx.x < 128) {
    int P = blockIdx.x * 256 + threadIdx.x;
    float x = pts[P*3+0], y = pts[P*3+1], z = pts[P*3+2];
    float xx = __fadd_rn(__fadd_rn(__fmul_rn(x,x), __fmul_rn(y,y)), __fmul_rn(z,z));
    pts4[P] = make_float4(x, y, z, xx);
  } else {
    int i = ((blockIdx.x - 128) * 256 + threadIdx.x) * 4;
    float4 w = *(const float4*)&Wc2[i];
    *(ushort4*)&wb[i] = make_ushort4(f2bf(w.x), f2bf(w.y), f2bf(w.z), f2bf(w.w));
  }
}

// ---------------------------------------------------------------- knn (R9 — measured 106 us local optimum)
#define KCAP 32
__global__ __launch_bounds__(256) void k_knn4(const float4* __restrict__ pts4,
                                              u64* __restrict__ pk) {
  __shared__ float4 cand[512];
  __shared__ u64 ring[KCAP+1][256];   // +1 guard row for prefetch at s+1
  const int tid = threadIdx.x;
  const int qg  = blockIdx.x;      // 0..127: query group of 256
  const int ch  = blockIdx.y;      // 0..3:   candidate chunk
  const int P   = qg * 256 + tid;  // global query point
  const float4* base = pts4 + ((P >> 11) << 11);
  const int j0 = ch << 9;
  for (int i = tid; i < 512; i += 256) cand[i] = base[j0 + i];
  const float4 q = base[P & (N_-1)];
  __syncthreads();

  u64 K[16];
#pragma unroll
  for (int t = 0; t < 16; ++t) K[t] = 0ull;   // 0 < any real key -> -inf sentinel
  u64 kmin = 0ull;
  int cnt = 0;

#define FLUSH4() do { \
    int s = 0; \
    u64 fk_next = ring[0][tid]; \
    while (__any(s < cnt)) { \
      u64 fk = (s < cnt) ? fk_next : 0ull; \
      fk_next = ring[s+1][tid]; \
      if (fk > kmin) { \
        _Pragma("unroll") \
        for (int t = 15; t > 0; --t) { \
          if (K[t] < fk) K[t] = (K[t-1] < fk) ? K[t-1] : fk; \
        } \
        if (K[0] < fk) K[0] = fk; \
        kmin = K[15]; \
      } \
      ++s; \
    } \
    cnt = 0; \
  } while (0)

  for (int jj = 0; jj < 512; jj += 4) {
    if (__any(cnt > KCAP - 4)) FLUSH4();
#pragma unroll
    for (int u = 0; u < 4; ++u) {
      float4 c = cand[jj + u];
      float inner = __fadd_rn(__fadd_rn(__fmul_rn(q.x,c.x), __fmul_rn(q.y,c.y)),
                              __fmul_rn(q.z,c.z));
      float dj = __fsub_rn(__fsub_rn(__fmul_rn(2.f, inner), q.w), c.w);
      unsigned int du = __float_as_uint(dj);
      unsigned int kd = du ^ (((unsigned int)((int)du >> 31)) | 0x80000000u);
      u64 key = ((u64)kd << 32) | (unsigned int)(~(j0 + jj + u));
      if (key > kmin) { ring[cnt][tid] = key; ++cnt; }
    }
  }
  FLUSH4();
#undef FLUSH4
#pragma unroll
  for (int t = 0; t < 16; ++t)
    pk[((size_t)P*4 + ch)*16 + t] = K[t];
}

// ---------------------------------------------------------------- merge four sorted-16 lists + local_cov + m1a
__device__ __forceinline__ void kmerge16(const u64* a, const u64* b, u64* m) {
#pragma unroll
  for (int t = 0; t < 16; ++t) m[t] = (a[t] >= b[15-t]) ? a[t] : b[15-t];
#pragma unroll
  for (int dd = 8; dd >= 1; dd >>= 1)
#pragma unroll
    for (int i = 0; i < 16; ++i)
      if ((i & dd) == 0) {
        int j = i + dd;
        if (m[i] < m[j]) { u64 t_ = m[i]; m[i] = m[j]; m[j] = t_; }
      }
}

__global__ __launch_bounds__(256) void k_mergecov(const u64* __restrict__ pk,
                                                  const float4* __restrict__ pts4,
                                                  const float* __restrict__ W,
                                                  const float* __restrict__ bias,
                                                  int* __restrict__ idx,
                                                  float* __restrict__ act0) {
  __shared__ float Wl[64*12];
  __shared__ float bl[64];
  const int tid = threadIdx.x;
  for (int i = tid; i < 768; i += 256) Wl[i] = W[i];
  if (tid < 64) bl[tid] = bias[tid];
  __syncthreads();

  int P = blockIdx.x * 256 + tid;
  const u64* row = pk + (size_t)P * 64;
  u64 L0[16], L1[16], A[16], B[16], M[16];
#pragma unroll
  for (int t = 0; t < 16; ++t) { L0[t] = row[t]; L1[t] = row[16+t]; }
  kmerge16(L0, L1, A);
#pragma unroll
  for (int t = 0; t < 16; ++t) { L0[t] = row[32+t]; L1[t] = row[48+t]; }
  kmerge16(L0, L1, B);
  kmerge16(A, B, M);
#pragma unroll
  for (int t = 0; t < 16; ++t)
    idx[(size_t)P*16 + t] = (int)(~(unsigned int)(M[t] & 0xFFFFFFFFull));

  const int j0 = (int)(~(unsigned int)(M[0] & 0xFFFFFFFFull));
  const int j1 = (int)(~(unsigned int)(M[1] & 0xFFFFFFFFull));
  const float4* base = pts4 + ((P >> 11) << 11);
  float4 p  = base[P & (N_-1)];
  float4 n0 = base[j0];
  float4 n1 = base[j1];
  float f[12];
  f[0]=p.x; f[1]=p.y; f[2]=p.z;
  f[3]=n0.x*n1.x; f[4]=n0.x*n1.y; f[5]=n0.x*n1.z;
  f[6]=n0.y*n1.x; f[7]=n0.y*n1.y; f[8]=n0.y*n1.z;
  f[9]=n0.z*n1.x; f[10]=n0.z*n1.y; f[11]=n0.z*n1.z;
  float* out = act0 + (size_t)P*64;
  for (int o4 = 0; o4 < 64; o4 += 4) {
    float4 v; float* vv = (float*)&v;
#pragma unroll
    for (int u = 0; u < 4; ++u) {
      int o = o4 + u;
      float acc = bl[o];
#pragma unroll
      for (int ci = 0; ci < 12; ++ci) acc += Wl[o*12+ci] * f[ci];
      vv[u] = fmaxf(acc, 0.f);
    }
    *(float4*)&out[o4] = v;
  }
}

// ---------------------------------------------------------------- fused m1b+m1c (64->64 relu, 64->64 relu)
__global__ __launch_bounds__(256) void k_m1bc(const float* __restrict__ X,
                                              const float* __restrict__ W1, const float* __restrict__ b1,
                                              const float* __restrict__ W2, const float* __restrict__ b2,
                                              float* __restrict__ Y) {
  __shared__ __align__(16) float Wt[64][68];
  __shared__ __align__(16) float Xt[64][68];
  const int tid = threadIdx.x;
  const int p0  = blockIdx.x * 64;
  const int cg = (tid & 15) * 4;
  const int pg = (tid >> 4) * 4;
  for (int i = tid; i < 4096; i += 256) {
    int r = i >> 6, k = i & 63;
    Wt[k][r] = W1[(size_t)r*64 + k];
    Xt[k][r] = X[(size_t)(p0 + r)*64 + k];
  }
  __syncthreads();
  float acc[4][4] = {{0.f,0.f,0.f,0.f},{0.f,0.f,0.f,0.f},{0.f,0.f,0.f,0.f},{0.f,0.f,0.f,0.f}};
#pragma unroll
  for (int k = 0; k < 64; ++k) {
    float4 wv = *(const float4*)&Wt[k][cg];
    float4 xv = *(const float4*)&Xt[k][pg];
    const float wr[4] = {wv.x, wv.y, wv.z, wv.w};
    const float xr[4] = {xv.x, xv.y, xv.z, xv.w};
#pragma unroll
    for (int i = 0; i < 4; ++i)
#pragma unroll
      for (int j = 0; j < 4; ++j)
        acc[i][j] += wr[i] * xr[j];
  }
  __syncthreads();
  float4 bv1 = *(const float4*)&b1[cg];
  const float br1[4] = {bv1.x, bv1.y, bv1.z, bv1.w};
#pragma unroll
  for (int i = 0; i < 4; ++i) {
    float4 v;
    v.x = fmaxf(acc[i][0] + br1[i], 0.f);
    v.y = fmaxf(acc[i][1] + br1[i], 0.f);
    v.z = fmaxf(acc[i][2] + br1[i], 0.f);
    v.w = fmaxf(acc[i][3] + br1[i], 0.f);
    *(float4*)&Xt[cg + i][pg] = v;
  }
  for (int i = tid; i < 4096; i += 256) {
    int r = i >> 6, k = i & 63;
    Wt[k][r] = W2[(size_t)r*64 + k];
  }
  __syncthreads();
  float ac2[4][4] = {{0.f,0.f,0.f,0.f},{0.f,0.f,0.f,0.f},{0.f,0.f,0.f,0.f},{0.f,0.f,0.f,0.f}};
#pragma unroll
  for (int k = 0; k < 64; ++k) {
    float4 wv = *(const float4*)&Wt[k][cg];
    float4 xv = *(const float4*)&Xt[k][pg];
    const float wr[4] = {wv.x, wv.y, wv.z, wv.w};
    const float xr[4] = {xv.x, xv.y, xv.z, xv.w};
#pragma unroll
    for (int i = 0; i < 4; ++i)
#pragma unroll
      for (int j = 0; j < 4; ++j)
        ac2[i][j] += wr[i] * xr[j];
  }
  float4 bv2 = *(const float4*)&b2[cg];
  const float br2[4] = {bv2.x, bv2.y, bv2.z, bv2.w};
#pragma unroll
  for (int j = 0; j < 4; ++j) {
    float4 st; float* sv = (float*)&st;
#pragma unroll
    for (int i = 0; i < 4; ++i) sv[i] = fmaxf(ac2[i][j] + br2[i], 0.f);
    *(float4*)&Y[(size_t)(p0 + pg + j)*64 + cg] = st;
  }
}

// ---------------------------------------------------------------- fused pool64 -> lin1 -> relu(c1): act1 -> act2 (P,128)
// R19: 512 threads/block (kept — measured best 344.9)
__global__ __launch_bounds__(512) void k_lin1c1(const float* __restrict__ A,   // act1 (P,64)
                                                const int* __restrict__ idx,
                                                const float* __restrict__ Wl1, const float* __restrict__ bl1,
                                                const float* __restrict__ Wc1, const float* __restrict__ bc1,
                                                float* __restrict__ Y) {       // act2 (P,128)
  __shared__ __align__(16) float Wt[64][68];
  __shared__ __align__(16) float Xt[64][68];
  __shared__ int il[1024];
  const int tid = threadIdx.x;            // 0..511
  const int p0  = blockIdx.x * 64;
  const int cg = (tid & 15) * 4;          // 16 col groups x 4
  const int pg = (tid >> 4) * 2;          // 32 pt groups x 2
  const int gr = tid >> 3;                // 64 points
  const int gk = (tid & 7) * 8;           // 8 channels each
  const float* Ab = A + (size_t)((p0 >> 11) << 11) * 64;
  *(int2*)&il[tid*2] = *(const int2*)&idx[(size_t)p0*16 + tid*2];
  for (int i = tid; i < 4096; i += 512) {
    int r = i >> 6, k = i & 63;
    Wt[k][r] = Wl1[(size_t)r*64 + k];
  }
  __syncthreads();
  {
    float4 mm[2];
    mm[0] = make_float4(-INFINITY,-INFINITY,-INFINITY,-INFINITY);
    mm[1] = mm[0];
    const int* ir = &il[gr*16];
#pragma unroll
    for (int nb = 0; nb < 16; ++nb) {
      int j = ir[nb];
      const float4* row = (const float4*)&Ab[(size_t)j*64 + gk];
      mm[0] = max4(mm[0], row[0]);
      mm[1] = max4(mm[1], row[1]);
    }
    const float* mf = (const float*)mm;
#pragma unroll
    for (int u = 0; u < 8; ++u) Xt[gk + u][gr] = mf[u];
  }
  __syncthreads();
  float acc[4][2] = {{0.f,0.f},{0.f,0.f},{0.f,0.f},{0.f,0.f}};
#pragma unroll
  for (int k = 0; k < 64; ++k) {
    float4 wv = *(const float4*)&Wt[k][cg];
    float2 xv = *(const float2*)&Xt[k][pg];
    const float wr[4] = {wv.x, wv.y, wv.z, wv.w};
    const float xr[2] = {xv.x, xv.y};
#pragma unroll
    for (int i = 0; i < 4; ++i)
#pragma unroll
      for (int j = 0; j < 2; ++j)
        acc[i][j] += wr[i] * xr[j];
  }
  __syncthreads();
  float4 bv = *(const float4*)&bl1[cg];
  const float br[4] = {bv.x, bv.y, bv.z, bv.w};
#pragma unroll
  for (int i = 0; i < 4; ++i) {
    float2 v;
    v.x = acc[i][0] + br[i];
    v.y = acc[i][1] + br[i];
    *(float2*)&Xt[cg + i][pg] = v;
  }
  for (int i = tid; i < 4096; i += 512) {
    int r = i >> 6, k = i & 63;
    Wt[k][r] = Wc1[(size_t)r*64 + k];
  }
  __syncthreads();
  float ac2[4][2] = {{0.f,0.f},{0.f,0.f},{0.f,0.f},{0.f,0.f}};
#pragma unroll
  for (int k = 0; k < 64; ++k) {
    float4 wv = *(const float4*)&Wt[k][cg];
    float2 xv = *(const float2*)&Xt[k][pg];
    const float wr[4] = {wv.x, wv.y, wv.z, wv.w};
    const float xr[2] = {xv.x, xv.y};
#pragma unroll
    for (int i = 0; i < 4; ++i)
#pragma unroll
      for (int j = 0; j < 2; ++j)
        ac2[i][j] += wr[i] * xr[j];
  }
  float4 bc0 = *(const float4*)&bc1[cg];
  const float bc0r[4] = {bc0.x, bc0.y, bc0.z, bc0.w};
#pragma unroll
  for (int j = 0; j < 2; ++j) {
    float4 st; float* sv = (float*)&st;
#pragma unroll
    for (int i = 0; i < 4; ++i) sv[i] = fmaxf(ac2[i][j] + bc0r[i], 0.f);
    *(float4*)&Y[(size_t)(p0 + pg + j)*128 + cg] = st;
  }
  __syncthreads();
  for (int i = tid; i < 4096; i += 512) {
    int r = i >> 6, k = i & 63;
    Wt[k][r] = Wc1[(size_t)(64 + r)*64 + k];
  }
  __syncthreads();
  float ac3[4][2] = {{0.f,0.f},{0.f,0.f},{0.f,0.f},{0.f,0.f}};
#pragma unroll
  for (int k = 0; k < 64; ++k) {
    float4 wv = *(const float4*)&Wt[k][cg];
    float2 xv = *(const float2*)&Xt[k][pg];
    const float wr[4] = {wv.x, wv.y, wv.z, wv.w};
    const float xr[2] = {xv.x, xv.y};
#pragma unroll
    for (int i = 0; i < 4; ++i)
#pragma unroll
      for (int j = 0; j < 2; ++j)
        ac3[i][j] += wr[i] * xr[j];
  }
  float4 bc4 = *(const float4*)&bc1[64 + cg];
  const float bc4r[4] = {bc4.x, bc4.y, bc4.z, bc4.w};
#pragma unroll
  for (int j = 0; j < 2; ++j) {
    float4 st; float* sv = (float*)&st;
#pragma unroll
    for (int i = 0; i < 4; ++i) sv[i] = fmaxf(ac3[i][j] + bc4r[i], 0.f);
    *(float4*)&Y[(size_t)(p0 + pg + j)*128 + 64 + cg] = st;
  }
}

// ---------------------------------------------------------------- pool128-gather fused into lin2 (128->128, bf16 out)
// R20: 512 threads/block, same 64co x 64pt tile, same kt->k accumulation order
// (bit-identical). lin2p was 2 waves/SIMD resident (R12: Occ 27%, VALU 22%,
// HBM 17% = latency-bound); 8 waves/block doubles resident waves. All prior
// failed lin2p changes altered the memory schedule — never the wave count.
__global__ __launch_bounds__(512) void k_lin2p(const float* __restrict__ A,   // act2 (P,128)
                                               const int* __restrict__ idx,
                                               const float* __restrict__ W,
                                               const float* __restrict__ bias,
                                               unsigned short* __restrict__ Y) {
  __shared__ __align__(16) float Wt[64][68];
  __shared__ __align__(16) float Xt[64][68];
  __shared__ int il[1024];
  const int tid = threadIdx.x;            // 0..511
  const int co0 = blockIdx.x * 64;
  const int p0  = blockIdx.y * 64;
  const int cg = (tid & 15) * 4;          // 16 col groups x 4
  const int pg = (tid >> 4) * 2;          // 32 pt groups x 2
  const int gr = tid >> 3;                // 64 points
  const int gk = (tid & 7) * 8;           // 8 channels each (of the kt half)
  const float* Ab = A + (size_t)((p0 >> 11) << 11) * 128;
  *(int2*)&il[tid*2] = *(const int2*)&idx[(size_t)p0*16 + tid*2];
  float acc[4][2] = {{0.f,0.f},{0.f,0.f},{0.f,0.f},{0.f,0.f}};
  for (int kt = 0; kt < 128; kt += 64) {
    __syncthreads();
    for (int i = tid; i < 4096; i += 512) {
      int r = i >> 6, k = i & 63;
      Wt[k][r] = W[(size_t)(co0 + r)*128 + kt + k];
    }
    {
      float4 mm[2];
      mm[0] = make_float4(-INFINITY,-INFINITY,-INFINITY,-INFINITY);
      mm[1] = mm[0];
      const int* ir = &il[gr*16];
#pragma unroll
      for (int nb = 0; nb < 16; ++nb) {
        int j = ir[nb];
        const float4* row = (const float4*)&Ab[(size_t)j*128 + kt + gk];
        mm[0] = max4(mm[0], row[0]);
        mm[1] = max4(mm[1], row[1]);
      }
      const float* mf = (const float*)mm;
#pragma unroll
      for (int u = 0; u < 8; ++u) Xt[gk + u][gr] = mf[u];
    }
    __syncthreads();
#pragma unroll
    for (int k = 0; k < 64; ++k) {
      float4 wv = *(const float4*)&Wt[k][cg];
      float2 xv = *(const float2*)&Xt[k][pg];
      const float wr[4] = {wv.x, wv.y, wv.z, wv.w};
      const float xr[2] = {xv.x, xv.y};
#pragma unroll
      for (int i = 0; i < 4; ++i)
#pragma unroll
        for (int j = 0; j < 2; ++j)
          acc[i][j] += wr[i] * xr[j];
    }
  }
  float4 bv = *(const float4*)&bias[co0 + cg];
  const float br[4] = {bv.x, bv.y, bv.z, bv.w};
#pragma unroll
  for (int j = 0; j < 2; ++j) {
    ushort4 st;
    st.x = f2bf(acc[0][j] + br[0]);
    st.y = f2bf(acc[1][j] + br[1]);
    st.z = f2bf(acc[2][j] + br[2]);
    st.w = f2bf(acc[3][j] + br[3]);
    *(ushort4*)&Y[(size_t)(p0 + pg + j)*128 + co0 + cg] = st;
  }
}

// ---------------------------------------------------------------- c2 (128->1024) bf16 MFMA, fused max (R11 — measured win)
__global__ __launch_bounds__(256) void k_c2max(const unsigned short* __restrict__ X,  // act3b (B*N,128) bf16
                                               const unsigned short* __restrict__ W,  // (1024,128) bf16
                                               float* __restrict__ part) {            // (B,1024,4)
  __shared__ __align__(16) unsigned short Alds[128*136];
  __shared__ float red[128][4];
  const int tid  = threadIdx.x;
  const int wave = tid >> 6, lane = tid & 63;
  const int co0  = blockIdx.x * 128;
  const int p0   = blockIdx.y * 512;
  const int b    = blockIdx.z;
  const unsigned short* Xb = X + ((size_t)b * N_ + p0) * 128;

  for (int i = tid; i < 2048; i += 256) {
    int r = i >> 4, k8 = (i & 15) * 8;
    *(short8*)&Alds[r*136 + k8] = *(const short8*)&W[(size_t)(co0 + r)*128 + k8];
  }

  const int l16 = lane & 15, quad = lane >> 4;
  float mx[8][4];
#pragma unroll
  for (int t = 0; t < 8; ++t)
#pragma unroll
    for (int r = 0; r < 4; ++r) mx[t][r] = -INFINITY;

  for (int sub = 0; sub < 4; ++sub) {
    const unsigned short* Xs = Xb + (size_t)sub * 128 * 128;
    short8 b0[4], b1[4];
#pragma unroll
    for (int k0 = 0; k0 < 4; ++k0) {
      const int kk = k0*32 + quad*8;
      b0[k0] = *(const short8*)&Xs[(size_t)(wave*32 +      l16)*128 + kk];
      b1[k0] = *(const short8*)&Xs[(size_t)(wave*32 + 16 + l16)*128 + kk];
    }
    if (sub == 0) __syncthreads();   // Alds ready (X loads independent)

    f32x4 acc[8][2];
#pragma unroll
    for (int t = 0; t < 8; ++t) { acc[t][0] = (f32x4)0.f; acc[t][1] = (f32x4)0.f; }
#pragma unroll
    for (int k0 = 0; k0 < 4; ++k0) {
      const int kk = k0*32 + quad*8;
#pragma unroll
      for (int t = 0; t < 8; ++t) {
        short8 af = *(const short8*)&Alds[(t*16 + l16)*136 + kk];
        acc[t][0] = __builtin_amdgcn_mfma_f32_16x16x32_bf16(af, b0[k0], acc[t][0], 0, 0, 0);
        acc[t][1] = __builtin_amdgcn_mfma_f32_16x16x32_bf16(af, b1[k0], acc[t][1], 0, 0, 0);
      }
    }
#pragma unroll
    for (int t = 0; t < 8; ++t)
#pragma unroll
      for (int r = 0; r < 4; ++r)
        mx[t][r] = fmaxf(mx[t][r], fmaxf(acc[t][0][r], acc[t][1][r]));
  }

#pragma unroll
  for (int t = 0; t < 8; ++t) {
#pragma unroll
    for (int r = 0; r < 4; ++r) {
      float m = mx[t][r];
      m = fmaxf(m, __shfl_xor(m, 1));
      m = fmaxf(m, __shfl_xor(m, 2));
      m = fmaxf(m, __shfl_xor(m, 4));
      m = fmaxf(m, __shfl_xor(m, 8));
      if (l16 == 0) red[t*16 + quad*4 + r][wave] = m;
    }
  }
  __syncthreads();
  if (tid < 128) {
    float m = fmaxf(fmaxf(red[tid][0], red[tid][1]), fmaxf(red[tid][2], red[tid][3]));
    part[((size_t)b*1024 + co0 + tid)*4 + blockIdx.y] = m;
  }
}

// ---------------------------------------------------------------- R18: c2red fused into m2aW (kept — ~+3-5us)
__global__ __launch_bounds__(256) void k_m2aG(const float* __restrict__ part,  // (B,1024,4)
                                              const float* __restrict__ bc2,
                                              const float* __restrict__ Wa,
                                              const float* __restrict__ ba,
                                              float* __restrict__ h1) {
  __shared__ __align__(16) float gl[1024];
  const int tid = threadIdx.x;
  const int b   = blockIdx.x >> 5;          // 0..15
  const int oc  = (blockIdx.x & 31) * 16;   // 16 outputs per block
  for (int i = tid; i < 1024; i += 256) {
    const float* p = part + ((size_t)b*1024 + i)*4;
    gl[i] = fmaxf(fmaxf(p[0], p[1]), fmaxf(p[2], p[3])) + bc2[i];
  }
  __syncthreads();
  const int wave = tid >> 6, lane = tid & 63;
  const float4* g4 = (const float4*)gl;
#pragma unroll
  for (int u = 0; u < 4; ++u) {
    const int o = oc + wave*4 + u;
    const float4* wr = (const float4*)(Wa + (size_t)o*1024);
    float a = 0.f;
#pragma unroll
    for (int t = 0; t < 4; ++t) {
      float4 w = wr[lane + t*64], v = g4[lane + t*64];
      a += w.x*v.x + w.y*v.y + w.z*v.z + w.w*v.w;
    }
    a += __shfl_xor(a, 1);  a += __shfl_xor(a, 2);  a += __shfl_xor(a, 4);
    a += __shfl_xor(a, 8);  a += __shfl_xor(a, 16); a += __shfl_xor(a, 32);
    if (lane == 0) h1[(size_t)b*512 + o] = fmaxf(a + ba[o], 0.f);
  }
}

__global__ __launch_bounds__(256) void k_m2bW(const float* __restrict__ h1,
                                              const float* __restrict__ Wb,
                                              const float* __restrict__ bb,
                                              float* __restrict__ h2) {
  __shared__ __align__(16) float hl[512];
  const int tid = threadIdx.x;
  const int b   = blockIdx.x >> 5;
  const int oc  = (blockIdx.x & 31) * 16;
  for (int i = tid; i < 512; i += 256) hl[i] = h1[(size_t)b*512 + i];
  __syncthreads();
  const int wave = tid >> 6, lane = tid & 63;
  const float4* h4 = (const float4*)hl;
#pragma unroll
  for (int u = 0; u < 4; ++u) {
    const int o = oc + wave*4 + u;
    const float4* wr = (const float4*)(Wb + (size_t)o*512);
    float a = 0.f;
#pragma unroll
    for (int t = 0; t < 2; ++t) {
      float4 w = wr[lane + t*64], v = h4[lane + t*64];
      a += w.x*v.x + w.y*v.y + w.z*v.z + w.w*v.w;
    }
    a += __shfl_xor(a, 1);  a += __shfl_xor(a, 2);  a += __shfl_xor(a, 4);
    a += __shfl_xor(a, 8);  a += __shfl_xor(a, 16); a += __shfl_xor(a, 32);
    if (lane == 0) h2[(size_t)b*512 + o] = a + bb[o];
  }
}

__global__ __launch_bounds__(256) void k_embW(const float* __restrict__ h2,
                                              const float* __restrict__ We,
                                              float* __restrict__ out) {
  __shared__ __align__(16) float hl[512];
  const int tid = threadIdx.x;
  const int b   = blockIdx.x >> 3;          // 0..15
  const int oc  = (blockIdx.x & 7) * 16;    // 128 outputs / 8 blocks
  for (int i = tid; i < 512; i += 256) hl[i] = h2[(size_t)b*512 + i];
  __syncthreads();
  const int wave = tid >> 6, lane = tid & 63;
  const float4* h4 = (const float4*)hl;
#pragma unroll
  for (int u = 0; u < 4; ++u) {
    const int o = oc + wave*4 + u;
    const float4* wr = (const float4*)(We + (size_t)o*512);
    float a = 0.f;
#pragma unroll
    for (int t = 0; t < 2; ++t) {
      float4 w = wr[lane + t*64], v = h4[lane + t*64];
      a += w.x*v.x + w.y*v.y + w.z*v.z + w.w*v.w;
    }
    a += __shfl_xor(a, 1);  a += __shfl_xor(a, 2);  a += __shfl_xor(a, 4);
    a += __shfl_xor(a, 8);  a += __shfl_xor(a, 16); a += __shfl_xor(a, 32);
    if (lane == 0) out[(size_t)b*128 + o] = a;
  }
}

// ---------------------------------------------------------------- launch
extern "C" void kernel_launch(void* const* d_in, const int* in_sizes, int n_in,
                              void* d_out, int out_size, void* d_ws, size_t ws_size,
                              hipStream_t stream) {
  const float* pts    = (const float*)d_in[0];
  const float* W_m1a  = (const float*)d_in[1];
  const float* b_m1a  = (const float*)d_in[2];
  const float* W_m1b  = (const float*)d_in[3];
  const float* b_m1b  = (const float*)d_in[4];
  const float* W_m1c  = (const float*)d_in[5];
  const float* b_m1c  = (const float*)d_in[6];
  const float* W_lin1 = (const float*)d_in[7];
  const float* b_lin1 = (const float*)d_in[8];
  const float* W_c1   = (const float*)d_in[9];
  const float* b_c1   = (const float*)d_in[10];
  const float* W_lin2 = (const float*)d_in[11];
  const float* b_lin2 = (const float*)d_in[12];
  const float* W_c2   = (const float*)d_in[13];
  const float* b_c2   = (const float*)d_in[14];
  const float* W_m2a  = (const float*)d_in[15];
  const float* b_m2a  = (const float*)d_in[16];
  const float* W_m2b  = (const float*)d_in[17];
  const float* b_m2b  = (const float*)d_in[18];
  const float* W_emb  = (const float*)d_in[19];
  float* out = (float*)d_out;

  char* ws = (char*)d_ws;
  const size_t MB = 1024*1024;
  // liveness-overlapped layout (peak 35 MB):
  float4* pts4 = (float4*)(ws + 0);                        // 512 KB, dead after mergecov
  unsigned short* wc2b = (unsigned short*)(ws + 512*1024); // 256 KB, live till c2max
  int*    idx  = (int*)  (ws + 1*MB);                      // 2 MB, live till lin2p
  u64*    pk   = (u64*)  (ws + 3*MB);                      // 16 MB keys, dead after mergecov
  float*  act0 = (float*)(ws + 19*MB);                     // 8 MB (P,64)
  float*  act1 = (float*)(ws + 3*MB);                      // 8 MB (P,64) — pk dead
  float*  act2 = (float*)(ws + 19*MB);                     // 16 MB (P,128) — act0 dead
  unsigned short* act3b = (unsigned short*)(ws + 3*MB);    // 8 MB bf16 (P,128) — act1 dead
  float*  part = (float*)(ws + 12*MB);                     // 256 KB (B,1024,4)
  float*  h1   = (float*)(ws + 0);                         // 32 KB (pts4 dead by tail)
  float*  h2   = (float*)(ws + 64*1024);                   // 32 KB

  k_prep2   <<<256, 256, 0, stream>>>(pts, W_c2, pts4, wc2b);
  k_knn4    <<<dim3(128, 4), 256, 0, stream>>>(pts4, pk);
  k_mergecov<<<128, 256, 0, stream>>>(pk, pts4, W_m1a, b_m1a, idx, act0);
  k_m1bc    <<<512, 256, 0, stream>>>(act0, W_m1b, b_m1b, W_m1c, b_m1c, act1);
  k_lin1c1  <<<512, 512, 0, stream>>>(act1, idx, W_lin1, b_lin1, W_c1, b_c1, act2);
  k_lin2p   <<<dim3(2,512), 512, 0, stream>>>(act2, idx, W_lin2, b_lin2, act3b);
  k_c2max   <<<dim3(8,4,16), 256, 0, stream>>>(act3b, wc2b, part);
  k_m2aG    <<<512, 256, 0, stream>>>(part, b_c2, W_m2a, b_m2a, h1);
  k_m2bW    <<<512, 256, 0, stream>>>(h1, W_m2b, b_m2b, h2);
  k_embW    <<<128, 256, 0, stream>>>(h2, W_emb, out);
}

// Round 20
// 328.032 us; speedup vs baseline: 1.2000x; 1.0325x over previous
//
#include <hip/hip_runtime.h>
#include <math.h>

#define N_   2048
#define NPTS 32768   // B*N = 16*2048

typedef __attribute__((ext_vector_type(8))) short short8;   // 8 bf16 (4 VGPRs)
typedef __attribute__((ext_vector_type(4))) float f32x4;
typedef unsigned long long u64;

__device__ __forceinline__ unsigned short f2bf(float f) {   // RTNE
  unsigned int u = __float_as_uint(f);
  return (unsigned short)((u + 0x7fffu + ((u >> 16) & 1u)) >> 16);
}
__device__ __forceinline__ float4 max4(float4 a, float4 b) {
  return make_float4(fmaxf(a.x,b.x), fmaxf(a.y,b.y), fmaxf(a.z,b.z), fmaxf(a.w,b.w));
}

// ---------------------------------------------------------------- prep (x,y,z,|p|^2) + W_c2->bf16
__global__ __launch_bounds__(256) void k_prep2(const float* __restrict__ pts,
                                               const float* __restrict__ Wc2,
                                               float4* __restrict__ pts4,
                                               unsigned short* __restrict__ wb) {
  if (blockIdx.x < 128) {
    int P = blockIdx.x * 256 + threadIdx.x;
    float x = pts[P*3+0], y = pts[P*3+1], z = pts[P*3+2];
    float xx = __fadd_rn(__fadd_rn(__fmul_rn(x,x), __fmul_rn(y,y)), __fmul_rn(z,z));
    pts4[P] = make_float4(x, y, z, xx);
  } else {
    int i = ((blockIdx.x - 128) * 256 + threadIdx.x) * 4;
    float4 w = *(const float4*)&Wc2[i];
    *(ushort4*)&wb[i] = make_ushort4(f2bf(w.x), f2bf(w.y), f2bf(w.z), f2bf(w.w));
  }
}

// ---------------------------------------------------------------- knn (R9 — measured 106 us local optimum)
#define KCAP 32
__global__ __launch_bounds__(256) void k_knn4(const float4* __restrict__ pts4,
                                              u64* __restrict__ pk) {
  __shared__ float4 cand[512];
  __shared__ u64 ring[KCAP+1][256];   // +1 guard row for prefetch at s+1
  const int tid = threadIdx.x;
  const int qg  = blockIdx.x;      // 0..127: query group of 256
  const int ch  = blockIdx.y;      // 0..3:   candidate chunk
  const int P   = qg * 256 + tid;  // global query point
  const float4* base = pts4 + ((P >> 11) << 11);
  const int j0 = ch << 9;
  for (int i = tid; i < 512; i += 256) cand[i] = base[j0 + i];
  const float4 q = base[P & (N_-1)];
  __syncthreads();

  u64 K[16];
#pragma unroll
  for (int t = 0; t < 16; ++t) K[t] = 0ull;   // 0 < any real key -> -inf sentinel
  u64 kmin = 0ull;
  int cnt = 0;

#define FLUSH4() do { \
    int s = 0; \
    u64 fk_next = ring[0][tid]; \
    while (__any(s < cnt)) { \
      u64 fk = (s < cnt) ? fk_next : 0ull; \
      fk_next = ring[s+1][tid]; \
      if (fk > kmin) { \
        _Pragma("unroll") \
        for (int t = 15; t > 0; --t) { \
          if (K[t] < fk) K[t] = (K[t-1] < fk) ? K[t-1] : fk; \
        } \
        if (K[0] < fk) K[0] = fk; \
        kmin = K[15]; \
      } \
      ++s; \
    } \
    cnt = 0; \
  } while (0)

  for (int jj = 0; jj < 512; jj += 4) {
    if (__any(cnt > KCAP - 4)) FLUSH4();
#pragma unroll
    for (int u = 0; u < 4; ++u) {
      float4 c = cand[jj + u];
      float inner = __fadd_rn(__fadd_rn(__fmul_rn(q.x,c.x), __fmul_rn(q.y,c.y)),
                              __fmul_rn(q.z,c.z));
      float dj = __fsub_rn(__fsub_rn(__fmul_rn(2.f, inner), q.w), c.w);
      unsigned int du = __float_as_uint(dj);
      unsigned int kd = du ^ (((unsigned int)((int)du >> 31)) | 0x80000000u);
      u64 key = ((u64)kd << 32) | (unsigned int)(~(j0 + jj + u));
      if (key > kmin) { ring[cnt][tid] = key; ++cnt; }
    }
  }
  FLUSH4();
#undef FLUSH4
#pragma unroll
  for (int t = 0; t < 16; ++t)
    pk[((size_t)P*4 + ch)*16 + t] = K[t];
}

// ---------------------------------------------------------------- R21: mergecov fused into m1bc as per-tile prologue.
// mergecov is per-point independent; m1bc consumes act0 only within its own
// 64-pt tile -> threads 0..63 merge pk, write idx, compute m1a directly into
// Xt[o][t] in LDS (the exact transposed layout m1bc staged from global).
// Saves 1 launch + 1 bubble + 16MB act0 round-trip. Aggregate merge
// parallelism unchanged (512 blk x 64 thr = 32K concurrent merges).
__device__ __forceinline__ void kmerge16(const u64* a, const u64* b, u64* m) {
#pragma unroll
  for (int t = 0; t < 16; ++t) m[t] = (a[t] >= b[15-t]) ? a[t] : b[15-t];
#pragma unroll
  for (int dd = 8; dd >= 1; dd >>= 1)
#pragma unroll
    for (int i = 0; i < 16; ++i)
      if ((i & dd) == 0) {
        int j = i + dd;
        if (m[i] < m[j]) { u64 t_ = m[i]; m[i] = m[j]; m[j] = t_; }
      }
}

__global__ __launch_bounds__(256) void k_mcbc(const u64* __restrict__ pk,
                                              const float4* __restrict__ pts4,
                                              const float* __restrict__ Wm1a,
                                              const float* __restrict__ bm1a,
                                              int* __restrict__ idx,
                                              const float* __restrict__ W1, const float* __restrict__ b1,
                                              const float* __restrict__ W2, const float* __restrict__ b2,
                                              float* __restrict__ Y) {
  __shared__ __align__(16) float Wt[64][68];
  __shared__ __align__(16) float Xt[64][68];
  __shared__ float Wl[64*12];
  __shared__ float bl[64];
  const int tid = threadIdx.x;
  const int p0  = blockIdx.x * 64;
  const int cg = (tid & 15) * 4;
  const int pg = (tid >> 4) * 4;
  // stage m1a weights + W1 (all threads)
  for (int i = tid; i < 768; i += 256) Wl[i] = Wm1a[i];
  if (tid < 64) bl[tid] = bm1a[tid];
  for (int i = tid; i < 4096; i += 256) {
    int r = i >> 6, k = i & 63;
    Wt[k][r] = W1[(size_t)r*64 + k];
  }
  __syncthreads();

  // ---- prologue: mergecov for this tile's 64 points (threads 0..63)
  if (tid < 64) {
    int P = p0 + tid;
    const u64* row = pk + (size_t)P * 64;
    u64 L0[16], L1[16], A[16], B[16], M[16];
#pragma unroll
    for (int t = 0; t < 16; ++t) { L0[t] = row[t]; L1[t] = row[16+t]; }
    kmerge16(L0, L1, A);
#pragma unroll
    for (int t = 0; t < 16; ++t) { L0[t] = row[32+t]; L1[t] = row[48+t]; }
    kmerge16(L0, L1, B);
    kmerge16(A, B, M);
#pragma unroll
    for (int t = 0; t < 16; ++t)
      idx[(size_t)P*16 + t] = (int)(~(unsigned int)(M[t] & 0xFFFFFFFFull));

    const int j0 = (int)(~(unsigned int)(M[0] & 0xFFFFFFFFull));
    const int j1 = (int)(~(unsigned int)(M[1] & 0xFFFFFFFFull));
    const float4* base = pts4 + ((P >> 11) << 11);
    float4 p  = base[P & (N_-1)];
    float4 n0 = base[j0];
    float4 n1 = base[j1];
    float f[12];
    f[0]=p.x; f[1]=p.y; f[2]=p.z;
    f[3]=n0.x*n1.x; f[4]=n0.x*n1.y; f[5]=n0.x*n1.z;
    f[6]=n0.y*n1.x; f[7]=n0.y*n1.y; f[8]=n0.y*n1.z;
    f[9]=n0.z*n1.x; f[10]=n0.z*n1.y; f[11]=n0.z*n1.z;
    for (int o4 = 0; o4 < 64; o4 += 4) {
#pragma unroll
      for (int u = 0; u < 4; ++u) {
        int o = o4 + u;
        float acc = bl[o];
#pragma unroll
        for (int ci = 0; ci < 12; ++ci) acc += Wl[o*12+ci] * f[ci];
        Xt[o][tid] = fmaxf(acc, 0.f);
      }
    }
  }
  __syncthreads();

  // ---- m1b GEMM (identical to old k_m1bc)
  float acc[4][4] = {{0.f,0.f,0.f,0.f},{0.f,0.f,0.f,0.f},{0.f,0.f,0.f,0.f},{0.f,0.f,0.f,0.f}};
#pragma unroll
  for (int k = 0; k < 64; ++k) {
    float4 wv = *(const float4*)&Wt[k][cg];
    float4 xv = *(const float4*)&Xt[k][pg];
    const float wr[4] = {wv.x, wv.y, wv.z, wv.w};
    const float xr[4] = {xv.x, xv.y, xv.z, xv.w};
#pragma unroll
    for (int i = 0; i < 4; ++i)
#pragma unroll
      for (int j = 0; j < 4; ++j)
        acc[i][j] += wr[i] * xr[j];
  }
  __syncthreads();
  float4 bv1 = *(const float4*)&b1[cg];
  const float br1[4] = {bv1.x, bv1.y, bv1.z, bv1.w};
#pragma unroll
  for (int i = 0; i < 4; ++i) {
    float4 v;
    v.x = fmaxf(acc[i][0] + br1[i], 0.f);
    v.y = fmaxf(acc[i][1] + br1[i], 0.f);
    v.z = fmaxf(acc[i][2] + br1[i], 0.f);
    v.w = fmaxf(acc[i][3] + br1[i], 0.f);
    *(float4*)&Xt[cg + i][pg] = v;
  }
  for (int i = tid; i < 4096; i += 256) {
    int r = i >> 6, k = i & 63;
    Wt[k][r] = W2[(size_t)r*64 + k];
  }
  __syncthreads();
  float ac2[4][4] = {{0.f,0.f,0.f,0.f},{0.f,0.f,0.f,0.f},{0.f,0.f,0.f,0.f},{0.f,0.f,0.f,0.f}};
#pragma unroll
  for (int k = 0; k < 64; ++k) {
    float4 wv = *(const float4*)&Wt[k][cg];
    float4 xv = *(const float4*)&Xt[k][pg];
    const float wr[4] = {wv.x, wv.y, wv.z, wv.w};
    const float xr[4] = {xv.x, xv.y, xv.z, xv.w};
#pragma unroll
    for (int i = 0; i < 4; ++i)
#pragma unroll
      for (int j = 0; j < 4; ++j)
        ac2[i][j] += wr[i] * xr[j];
  }
  float4 bv2 = *(const float4*)&b2[cg];
  const float br2[4] = {bv2.x, bv2.y, bv2.z, bv2.w};
#pragma unroll
  for (int j = 0; j < 4; ++j) {
    float4 st; float* sv = (float*)&st;
#pragma unroll
    for (int i = 0; i < 4; ++i) sv[i] = fmaxf(ac2[i][j] + br2[i], 0.f);
    *(float4*)&Y[(size_t)(p0 + pg + j)*64 + cg] = st;
  }
}

// ---------------------------------------------------------------- fused pool64 -> lin1 -> relu(c1): act1 -> act2 (P,128)
// R19: 512 threads/block (kept — measured best)
__global__ __launch_bounds__(512) void k_lin1c1(const float* __restrict__ A,   // act1 (P,64)
                                                const int* __restrict__ idx,
                                                const float* __restrict__ Wl1, const float* __restrict__ bl1,
                                                const float* __restrict__ Wc1, const float* __restrict__ bc1,
                                                float* __restrict__ Y) {       // act2 (P,128)
  __shared__ __align__(16) float Wt[64][68];
  __shared__ __align__(16) float Xt[64][68];
  __shared__ int il[1024];
  const int tid = threadIdx.x;            // 0..511
  const int p0  = blockIdx.x * 64;
  const int cg = (tid & 15) * 4;          // 16 col groups x 4
  const int pg = (tid >> 4) * 2;          // 32 pt groups x 2
  const int gr = tid >> 3;                // 64 points
  const int gk = (tid & 7) * 8;           // 8 channels each
  const float* Ab = A + (size_t)((p0 >> 11) << 11) * 64;
  *(int2*)&il[tid*2] = *(const int2*)&idx[(size_t)p0*16 + tid*2];
  for (int i = tid; i < 4096; i += 512) {
    int r = i >> 6, k = i & 63;
    Wt[k][r] = Wl1[(size_t)r*64 + k];
  }
  __syncthreads();
  {
    float4 mm[2];
    mm[0] = make_float4(-INFINITY,-INFINITY,-INFINITY,-INFINITY);
    mm[1] = mm[0];
    const int* ir = &il[gr*16];
#pragma unroll
    for (int nb = 0; nb < 16; ++nb) {
      int j = ir[nb];
      const float4* row = (const float4*)&Ab[(size_t)j*64 + gk];
      mm[0] = max4(mm[0], row[0]);
      mm[1] = max4(mm[1], row[1]);
    }
    const float* mf = (const float*)mm;
#pragma unroll
    for (int u = 0; u < 8; ++u) Xt[gk + u][gr] = mf[u];
  }
  __syncthreads();
  float acc[4][2] = {{0.f,0.f},{0.f,0.f},{0.f,0.f},{0.f,0.f}};
#pragma unroll
  for (int k = 0; k < 64; ++k) {
    float4 wv = *(const float4*)&Wt[k][cg];
    float2 xv = *(const float2*)&Xt[k][pg];
    const float wr[4] = {wv.x, wv.y, wv.z, wv.w};
    const float xr[2] = {xv.x, xv.y};
#pragma unroll
    for (int i = 0; i < 4; ++i)
#pragma unroll
      for (int j = 0; j < 2; ++j)
        acc[i][j] += wr[i] * xr[j];
  }
  __syncthreads();
  float4 bv = *(const float4*)&bl1[cg];
  const float br[4] = {bv.x, bv.y, bv.z, bv.w};
#pragma unroll
  for (int i = 0; i < 4; ++i) {
    float2 v;
    v.x = acc[i][0] + br[i];
    v.y = acc[i][1] + br[i];
    *(float2*)&Xt[cg + i][pg] = v;
  }
  for (int i = tid; i < 4096; i += 512) {
    int r = i >> 6, k = i & 63;
    Wt[k][r] = Wc1[(size_t)r*64 + k];
  }
  __syncthreads();
  float ac2[4][2] = {{0.f,0.f},{0.f,0.f},{0.f,0.f},{0.f,0.f}};
#pragma unroll
  for (int k = 0; k < 64; ++k) {
    float4 wv = *(const float4*)&Wt[k][cg];
    float2 xv = *(const float2*)&Xt[k][pg];
    const float wr[4] = {wv.x, wv.y, wv.z, wv.w};
    const float xr[2] = {xv.x, xv.y};
#pragma unroll
    for (int i = 0; i < 4; ++i)
#pragma unroll
      for (int j = 0; j < 2; ++j)
        ac2[i][j] += wr[i] * xr[j];
  }
  float4 bc0 = *(const float4*)&bc1[cg];
  const float bc0r[4] = {bc0.x, bc0.y, bc0.z, bc0.w};
#pragma unroll
  for (int j = 0; j < 2; ++j) {
    float4 st; float* sv = (float*)&st;
#pragma unroll
    for (int i = 0; i < 4; ++i) sv[i] = fmaxf(ac2[i][j] + bc0r[i], 0.f);
    *(float4*)&Y[(size_t)(p0 + pg + j)*128 + cg] = st;
  }
  __syncthreads();
  for (int i = tid; i < 4096; i += 512) {
    int r = i >> 6, k = i & 63;
    Wt[k][r] = Wc1[(size_t)(64 + r)*64 + k];
  }
  __syncthreads();
  float ac3[4][2] = {{0.f,0.f},{0.f,0.f},{0.f,0.f},{0.f,0.f}};
#pragma unroll
  for (int k = 0; k < 64; ++k) {
    float4 wv = *(const float4*)&Wt[k][cg];
    float2 xv = *(const float2*)&Xt[k][pg];
    const float wr[4] = {wv.x, wv.y, wv.z, wv.w};
    const float xr[2] = {xv.x, xv.y};
#pragma unroll
    for (int i = 0; i < 4; ++i)
#pragma unroll
      for (int j = 0; j < 2; ++j)
        ac3[i][j] += wr[i] * xr[j];
  }
  float4 bc4 = *(const float4*)&bc1[64 + cg];
  const float bc4r[4] = {bc4.x, bc4.y, bc4.z, bc4.w};
#pragma unroll
  for (int j = 0; j < 2; ++j) {
    float4 st; float* sv = (float*)&st;
#pragma unroll
    for (int i = 0; i < 4; ++i) sv[i] = fmaxf(ac3[i][j] + bc4r[i], 0.f);
    *(float4*)&Y[(size_t)(p0 + pg + j)*128 + 64 + cg] = st;
  }
}

// ---------------------------------------------------------------- pool128-gather fused into lin2 (128->128, bf16 out)
// R20: 512 threads/block (measured win: lin2p 57 -> ~51)
__global__ __launch_bounds__(512) void k_lin2p(const float* __restrict__ A,   // act2 (P,128)
                                               const int* __restrict__ idx,
                                               const float* __restrict__ W,
                                               const float* __restrict__ bias,
                                               unsigned short* __restrict__ Y) {
  __shared__ __align__(16) float Wt[64][68];
  __shared__ __align__(16) float Xt[64][68];
  __shared__ int il[1024];
  const int tid = threadIdx.x;            // 0..511
  const int co0 = blockIdx.x * 64;
  const int p0  = blockIdx.y * 64;
  const int cg = (tid & 15) * 4;          // 16 col groups x 4
  const int pg = (tid >> 4) * 2;          // 32 pt groups x 2
  const int gr = tid >> 3;                // 64 points
  const int gk = (tid & 7) * 8;           // 8 channels each (of the kt half)
  const float* Ab = A + (size_t)((p0 >> 11) << 11) * 128;
  *(int2*)&il[tid*2] = *(const int2*)&idx[(size_t)p0*16 + tid*2];
  float acc[4][2] = {{0.f,0.f},{0.f,0.f},{0.f,0.f},{0.f,0.f}};
  for (int kt = 0; kt < 128; kt += 64) {
    __syncthreads();
    for (int i = tid; i < 4096; i += 512) {
      int r = i >> 6, k = i & 63;
      Wt[k][r] = W[(size_t)(co0 + r)*128 + kt + k];
    }
    {
      float4 mm[2];
      mm[0] = make_float4(-INFINITY,-INFINITY,-INFINITY,-INFINITY);
      mm[1] = mm[0];
      const int* ir = &il[gr*16];
#pragma unroll
      for (int nb = 0; nb < 16; ++nb) {
        int j = ir[nb];
        const float4* row = (const float4*)&Ab[(size_t)j*128 + kt + gk];
        mm[0] = max4(mm[0], row[0]);
        mm[1] = max4(mm[1], row[1]);
      }
      const float* mf = (const float*)mm;
#pragma unroll
      for (int u = 0; u < 8; ++u) Xt[gk + u][gr] = mf[u];
    }
    __syncthreads();
#pragma unroll
    for (int k = 0; k < 64; ++k) {
      float4 wv = *(const float4*)&Wt[k][cg];
      float2 xv = *(const float2*)&Xt[k][pg];
      const float wr[4] = {wv.x, wv.y, wv.z, wv.w};
      const float xr[2] = {xv.x, xv.y};
#pragma unroll
      for (int i = 0; i < 4; ++i)
#pragma unroll
        for (int j = 0; j < 2; ++j)
          acc[i][j] += wr[i] * xr[j];
    }
  }
  float4 bv = *(const float4*)&bias[co0 + cg];
  const float br[4] = {bv.x, bv.y, bv.z, bv.w};
#pragma unroll
  for (int j = 0; j < 2; ++j) {
    ushort4 st;
    st.x = f2bf(acc[0][j] + br[0]);
    st.y = f2bf(acc[1][j] + br[1]);
    st.z = f2bf(acc[2][j] + br[2]);
    st.w = f2bf(acc[3][j] + br[3]);
    *(ushort4*)&Y[(size_t)(p0 + pg + j)*128 + co0 + cg] = st;
  }
}

// ---------------------------------------------------------------- c2 (128->1024) bf16 MFMA, fused max (R11 — measured win)
__global__ __launch_bounds__(256) void k_c2max(const unsigned short* __restrict__ X,  // act3b (B*N,128) bf16
                                               const unsigned short* __restrict__ W,  // (1024,128) bf16
                                               float* __restrict__ part) {            // (B,1024,4)
  __shared__ __align__(16) unsigned short Alds[128*136];
  __shared__ float red[128][4];
  const int tid  = threadIdx.x;
  const int wave = tid >> 6, lane = tid & 63;
  const int co0  = blockIdx.x * 128;
  const int p0   = blockIdx.y * 512;
  const int b    = blockIdx.z;
  const unsigned short* Xb = X + ((size_t)b * N_ + p0) * 128;

  for (int i = tid; i < 2048; i += 256) {
    int r = i >> 4, k8 = (i & 15) * 8;
    *(short8*)&Alds[r*136 + k8] = *(const short8*)&W[(size_t)(co0 + r)*128 + k8];
  }

  const int l16 = lane & 15, quad = lane >> 4;
  float mx[8][4];
#pragma unroll
  for (int t = 0; t < 8; ++t)
#pragma unroll
    for (int r = 0; r < 4; ++r) mx[t][r] = -INFINITY;

  for (int sub = 0; sub < 4; ++sub) {
    const unsigned short* Xs = Xb + (size_t)sub * 128 * 128;
    short8 b0[4], b1[4];
#pragma unroll
    for (int k0 = 0; k0 < 4; ++k0) {
      const int kk = k0*32 + quad*8;
      b0[k0] = *(const short8*)&Xs[(size_t)(wave*32 +      l16)*128 + kk];
      b1[k0] = *(const short8*)&Xs[(size_t)(wave*32 + 16 + l16)*128 + kk];
    }
    if (sub == 0) __syncthreads();   // Alds ready (X loads independent)

    f32x4 acc[8][2];
#pragma unroll
    for (int t = 0; t < 8; ++t) { acc[t][0] = (f32x4)0.f; acc[t][1] = (f32x4)0.f; }
#pragma unroll
    for (int k0 = 0; k0 < 4; ++k0) {
      const int kk = k0*32 + quad*8;
#pragma unroll
      for (int t = 0; t < 8; ++t) {
        short8 af = *(const short8*)&Alds[(t*16 + l16)*136 + kk];
        acc[t][0] = __builtin_amdgcn_mfma_f32_16x16x32_bf16(af, b0[k0], acc[t][0], 0, 0, 0);
        acc[t][1] = __builtin_amdgcn_mfma_f32_16x16x32_bf16(af, b1[k0], acc[t][1], 0, 0, 0);
      }
    }
#pragma unroll
    for (int t = 0; t < 8; ++t)
#pragma unroll
      for (int r = 0; r < 4; ++r)
        mx[t][r] = fmaxf(mx[t][r], fmaxf(acc[t][0][r], acc[t][1][r]));
  }

#pragma unroll
  for (int t = 0; t < 8; ++t) {
#pragma unroll
    for (int r = 0; r < 4; ++r) {
      float m = mx[t][r];
      m = fmaxf(m, __shfl_xor(m, 1));
      m = fmaxf(m, __shfl_xor(m, 2));
      m = fmaxf(m, __shfl_xor(m, 4));
      m = fmaxf(m, __shfl_xor(m, 8));
      if (l16 == 0) red[t*16 + quad*4 + r][wave] = m;
    }
  }
  __syncthreads();
  if (tid < 128) {
    float m = fmaxf(fmaxf(red[tid][0], red[tid][1]), fmaxf(red[tid][2], red[tid][3]));
    part[((size_t)b*1024 + co0 + tid)*4 + blockIdx.y] = m;
  }
}

// ---------------------------------------------------------------- R18: c2red fused into m2aW (kept — measured win)
__global__ __launch_bounds__(256) void k_m2aG(const float* __restrict__ part,  // (B,1024,4)
                                              const float* __restrict__ bc2,
                                              const float* __restrict__ Wa,
                                              const float* __restrict__ ba,
                                              float* __restrict__ h1) {
  __shared__ __align__(16) float gl[1024];
  const int tid = threadIdx.x;
  const int b   = blockIdx.x >> 5;          // 0..15
  const int oc  = (blockIdx.x & 31) * 16;   // 16 outputs per block
  for (int i = tid; i < 1024; i += 256) {
    const float* p = part + ((size_t)b*1024 + i)*4;
    gl[i] = fmaxf(fmaxf(p[0], p[1]), fmaxf(p[2], p[3])) + bc2[i];
  }
  __syncthreads();
  const int wave = tid >> 6, lane = tid & 63;
  const float4* g4 = (const float4*)gl;
#pragma unroll
  for (int u = 0; u < 4; ++u) {
    const int o = oc + wave*4 + u;
    const float4* wr = (const float4*)(Wa + (size_t)o*1024);
    float a = 0.f;
#pragma unroll
    for (int t = 0; t < 4; ++t) {
      float4 w = wr[lane + t*64], v = g4[lane + t*64];
      a += w.x*v.x + w.y*v.y + w.z*v.z + w.w*v.w;
    }
    a += __shfl_xor(a, 1);  a += __shfl_xor(a, 2);  a += __shfl_xor(a, 4);
    a += __shfl_xor(a, 8);  a += __shfl_xor(a, 16); a += __shfl_xor(a, 32);
    if (lane == 0) h1[(size_t)b*512 + o] = fmaxf(a + ba[o], 0.f);
  }
}

__global__ __launch_bounds__(256) void k_m2bW(const float* __restrict__ h1,
                                              const float* __restrict__ Wb,
                                              const float* __restrict__ bb,
                                              float* __restrict__ h2) {
  __shared__ __align__(16) float hl[512];
  const int tid = threadIdx.x;
  const int b   = blockIdx.x >> 5;
  const int oc  = (blockIdx.x & 31) * 16;
  for (int i = tid; i < 512; i += 256) hl[i] = h1[(size_t)b*512 + i];
  __syncthreads();
  const int wave = tid >> 6, lane = tid & 63;
  const float4* h4 = (const float4*)hl;
#pragma unroll
  for (int u = 0; u < 4; ++u) {
    const int o = oc + wave*4 + u;
    const float4* wr = (const float4*)(Wb + (size_t)o*512);
    float a = 0.f;
#pragma unroll
    for (int t = 0; t < 2; ++t) {
      float4 w = wr[lane + t*64], v = h4[lane + t*64];
      a += w.x*v.x + w.y*v.y + w.z*v.z + w.w*v.w;
    }
    a += __shfl_xor(a, 1);  a += __shfl_xor(a, 2);  a += __shfl_xor(a, 4);
    a += __shfl_xor(a, 8);  a += __shfl_xor(a, 16); a += __shfl_xor(a, 32);
    if (lane == 0) h2[(size_t)b*512 + o] = a + bb[o];
  }
}

__global__ __launch_bounds__(256) void k_embW(const float* __restrict__ h2,
                                              const float* __restrict__ We,
                                              float* __restrict__ out) {
  __shared__ __align__(16) float hl[512];
  const int tid = threadIdx.x;
  const int b   = blockIdx.x >> 3;          // 0..15
  const int oc  = (blockIdx.x & 7) * 16;    // 128 outputs / 8 blocks
  for (int i = tid; i < 512; i += 256) hl[i] = h2[(size_t)b*512 + i];
  __syncthreads();
  const int wave = tid >> 6, lane = tid & 63;
  const float4* h4 = (const float4*)hl;
#pragma unroll
  for (int u = 0; u < 4; ++u) {
    const int o = oc + wave*4 + u;
    const float4* wr = (const float4*)(We + (size_t)o*512);
    float a = 0.f;
#pragma unroll
    for (int t = 0; t < 2; ++t) {
      float4 w = wr[lane + t*64], v = h4[lane + t*64];
      a += w.x*v.x + w.y*v.y + w.z*v.z + w.w*v.w;
    }
    a += __shfl_xor(a, 1);  a += __shfl_xor(a, 2);  a += __shfl_xor(a, 4);
    a += __shfl_xor(a, 8);  a += __shfl_xor(a, 16); a += __shfl_xor(a, 32);
    if (lane == 0) out[(size_t)b*128 + o] = a;
  }
}

// ---------------------------------------------------------------- launch
extern "C" void kernel_launch(void* const* d_in, const int* in_sizes, int n_in,
                              void* d_out, int out_size, void* d_ws, size_t ws_size,
                              hipStream_t stream) {
  const float* pts    = (const float*)d_in[0];
  const float* W_m1a  = (const float*)d_in[1];
  const float* b_m1a  = (const float*)d_in[2];
  const float* W_m1b  = (const float*)d_in[3];
  const float* b_m1b  = (const float*)d_in[4];
  const float* W_m1c  = (const float*)d_in[5];
  const float* b_m1c  = (const float*)d_in[6];
  const float* W_lin1 = (const float*)d_in[7];
  const float* b_lin1 = (const float*)d_in[8];
  const float* W_c1   = (const float*)d_in[9];
  const float* b_c1   = (const float*)d_in[10];
  const float* W_lin2 = (const float*)d_in[11];
  const float* b_lin2 = (const float*)d_in[12];
  const float* W_c2   = (const float*)d_in[13];
  const float* b_c2   = (const float*)d_in[14];
  const float* W_m2a  = (const float*)d_in[15];
  const float* b_m2a  = (const float*)d_in[16];
  const float* W_m2b  = (const float*)d_in[17];
  const float* b_m2b  = (const float*)d_in[18];
  const float* W_emb  = (const float*)d_in[19];
  float* out = (float*)d_out;

  char* ws = (char*)d_ws;
  const size_t MB = 1024*1024;
  // liveness-overlapped layout (peak 35 MB):
  float4* pts4 = (float4*)(ws + 0);                        // 512 KB, dead after mcbc
  unsigned short* wc2b = (unsigned short*)(ws + 512*1024); // 256 KB, live till c2max
  int*    idx  = (int*)  (ws + 1*MB);                      // 2 MB, live till lin2p
  u64*    pk   = (u64*)  (ws + 3*MB);                      // 16 MB keys, dead after mcbc
  float*  act1 = (float*)(ws + 19*MB);                     // 8 MB (P,64)
  float*  act2 = (float*)(ws + 27*MB);                     // 16 MB (P,128)
  unsigned short* act3b = (unsigned short*)(ws + 3*MB);    // 8 MB bf16 (P,128) — pk dead
  float*  part = (float*)(ws + 12*MB);                     // 256 KB (B,1024,4)
  float*  h1   = (float*)(ws + 0);                         // 32 KB (pts4 dead by tail)
  float*  h2   = (float*)(ws + 64*1024);                   // 32 KB

  k_prep2   <<<256, 256, 0, stream>>>(pts, W_c2, pts4, wc2b);
  k_knn4    <<<dim3(128, 4), 256, 0, stream>>>(pts4, pk);
  k_mcbc    <<<512, 256, 0, stream>>>(pk, pts4, W_m1a, b_m1a, idx, W_m1b, b_m1b, W_m1c, b_m1c, act1);
  k_lin1c1  <<<512, 512, 0, stream>>>(act1, idx, W_lin1, b_lin1, W_c1, b_c1, act2);
  k_lin2p   <<<dim3(2,512), 512, 0, stream>>>(act2, idx, W_lin2, b_lin2, act3b);
  k_c2max   <<<dim3(8,4,16), 256, 0, stream>>>(act3b, wc2b, part);
  k_m2aG    <<<512, 256, 0, stream>>>(part, b_c2, W_m2a, b_m2a, h1);
  k_m2bW    <<<512, 256, 0, stream>>>(h1, W_m2b, b_m2b, h2);
  k_embW    <<<128, 256, 0, stream>>>(h2, W_emb, out);
}